// Round 2
// baseline (1639.298 us; speedup 1.0000x reference)
//
#include <hip/hip_runtime.h>
#include <hip/hip_bf16.h>
#include <math.h>

#define PI_F 3.14159265358979323846f
#define R0_F 5.0f

// wave-local LDS ordering: all producer/consumer pairs are within one wave,
// so a full lgkmcnt drain replaces __syncthreads (no s_barrier needed).
#define WAVE_SYNC() asm volatile("s_waitcnt lgkmcnt(0)" ::: "memory")

// ---------------------------------------------------------------------------
// ws layout:
//   P[n][816] float : per-node input projections
//     [0,48)    Pa[k*16+r]                 k=0:pa000,1:pa011,2:pa022
//     [48,240)  Pv[48+k*48+3r+i]           k=0:pv101,1:pv110,2:pv112,3:pv121
//     [240,816) Pd[240+k*144+9r+ij]        k=0:pd202,1:pd211,2:pd220,3:pd222
//   counts[N] | offs[N+1] | cursor[N] | eidx[E]   (ints, CSR by src)
// ---------------------------------------------------------------------------

static __device__ __forceinline__ float dot4(float4 a, float4 b) {
  return a.x * b.x + a.y * b.y + a.z * b.z + a.w * b.w;
}

// ------------------- K1: per-node input projections (v2) --------------------
__global__ __launch_bounds__(256) void node_proj_kernel(
    const float* __restrict__ x_a, const float* __restrict__ x_v, const float* __restrict__ x_d,
    const float* __restrict__ W1_a, const float* __restrict__ W1_v, const float* __restrict__ W1_d,
    float* __restrict__ P, int N)
{
  __shared__ float S[12352];           // 48.25 KB, reused each phase
  const int tid = threadIdx.x;
  const int lane = tid & 63;
  const int wu = __builtin_amdgcn_readfirstlane(tid >> 6);  // uniform wave id 0..3
  const int n0 = blockIdx.x * 64;
  const int nrem = min(N - n0, 64);    // valid nodes in this block

  // ===================== Phase A: xa(128) -> Pa (48 slots) ==================
  for (int idx4 = tid; idx4 < nrem * 32; idx4 += 256) {
    int n = idx4 >> 5, c4 = idx4 & 31;
    float4 v = ((const float4*)(x_a + (size_t)(n0 + n) * 128))[c4];
    float* d = &S[n * 129 + c4 * 4];
    d[0] = v.x; d[1] = v.y; d[2] = v.z; d[3] = v.w;
  }
  __syncthreads();
  {
    float acc[12];
    #pragma unroll
    for (int q = 0; q < 12; q++) acc[q] = 0.0f;
    const float* xrow = &S[lane * 129];
    for (int c0 = 0; c0 < 128; c0 += 16) {
      float xr[16];
      #pragma unroll
      for (int j = 0; j < 16; j++) xr[j] = xrow[c0 + j];
      #pragma unroll
      for (int q = 0; q < 12; q++) {
        int o = wu * 12 + q;                       // uniform: slot = k*16+r = o
        const float* wp = W1_a + (o >> 4) * 2048 + (o & 15) * 128 + c0;
        float s = 0.0f;
        #pragma unroll
        for (int j = 0; j < 16; j++) s += wp[j] * xr[j];
        acc[q] += s;
      }
    }
    __syncthreads();
    #pragma unroll
    for (int q = 0; q < 12; q++) S[lane * 49 + wu * 12 + q] = acc[q];
    __syncthreads();
    for (int u = tid; u < nrem * 12; u += 256) {
      int n = u / 12, m4 = u - n * 12;
      const float* s = &S[n * 49 + m4 * 4];
      ((float4*)(P + (size_t)(n0 + n) * 816))[m4] = make_float4(s[0], s[1], s[2], s[3]);
    }
  }
  __syncthreads();

  // ===================== Phase V: xv(64,3) -> Pv (192 slots) ================
  for (int idx4 = tid; idx4 < nrem * 48; idx4 += 256) {
    int n = idx4 / 48, m4 = idx4 - n * 48;
    float4 v = ((const float4*)(x_v + (size_t)(n0 + n) * 192))[m4];
    float* d = &S[n * 193 + m4 * 4];
    d[0] = v.x; d[1] = v.y; d[2] = v.z; d[3] = v.w;
  }
  __syncthreads();
  {
    float acc[16][3];
    #pragma unroll
    for (int r = 0; r < 16; r++)
      #pragma unroll
      for (int i = 0; i < 3; i++) acc[r][i] = 0.0f;
    const float* xrow = &S[lane * 193];
    for (int c0 = 0; c0 < 64; c0 += 16) {
      float xr[16][3];
      #pragma unroll
      for (int j = 0; j < 16; j++) {
        xr[j][0] = xrow[(c0 + j) * 3 + 0];
        xr[j][1] = xrow[(c0 + j) * 3 + 1];
        xr[j][2] = xrow[(c0 + j) * 3 + 2];
      }
      #pragma unroll
      for (int r = 0; r < 16; r++) {
        const float* wp = W1_v + wu * 1024 + r * 64 + c0;  // uniform, k = wu
        #pragma unroll
        for (int j = 0; j < 16; j++) {
          float w = wp[j];
          acc[r][0] += w * xr[j][0];
          acc[r][1] += w * xr[j][1];
          acc[r][2] += w * xr[j][2];
        }
      }
    }
    __syncthreads();
    #pragma unroll
    for (int r = 0; r < 16; r++)
      #pragma unroll
      for (int i = 0; i < 3; i++)
        S[lane * 193 + wu * 48 + r * 3 + i] = acc[r][i];
    __syncthreads();
    for (int u = tid; u < nrem * 48; u += 256) {
      int n = u / 48, m4 = u - n * 48;
      const float* s = &S[n * 193 + m4 * 4];
      ((float4*)(P + (size_t)(n0 + n) * 816 + 48))[m4] = make_float4(s[0], s[1], s[2], s[3]);
    }
  }
  __syncthreads();

  // ============== Phase D1: xd(32, ij=0..4) -> Pd slots ij<5 (320) ==========
  for (int idx = tid; idx < nrem * 160; idx += 256) {
    int n = idx / 160, m = idx - n * 160, c = m / 5, ij = m - c * 5;
    S[n * 161 + m] = x_d[(size_t)(n0 + n) * 288 + c * 9 + ij];
  }
  __syncthreads();
  {
    float acc[16][5];
    #pragma unroll
    for (int r = 0; r < 16; r++)
      #pragma unroll
      for (int t = 0; t < 5; t++) acc[r][t] = 0.0f;
    const float* xrow = &S[lane * 161];
    for (int c0 = 0; c0 < 32; c0 += 8) {
      float xr[8][5];
      #pragma unroll
      for (int j = 0; j < 8; j++)
        #pragma unroll
        for (int t = 0; t < 5; t++) xr[j][t] = xrow[(c0 + j) * 5 + t];
      #pragma unroll
      for (int r = 0; r < 16; r++) {
        const float* wp = W1_d + wu * 512 + r * 32 + c0;   // uniform, k = wu
        #pragma unroll
        for (int j = 0; j < 8; j++) {
          float w = wp[j];
          #pragma unroll
          for (int t = 0; t < 5; t++) acc[r][t] += w * xr[j][t];
        }
      }
    }
    #pragma unroll
    for (int h = 0; h < 2; h++) {
      __syncthreads();
      if ((lane >> 5) == h) {
        int l5 = lane & 31;
        #pragma unroll
        for (int r = 0; r < 16; r++)
          #pragma unroll
          for (int t = 0; t < 5; t++)
            S[l5 * 321 + wu * 80 + r * 5 + t] = acc[r][t];
      }
      __syncthreads();
      int nbase = h * 32;
      int cnt = min(nrem - nbase, 32);
      for (int u = tid; u < cnt * 320; u += 256) {
        int n = u / 320, m = u - n * 320;
        int kk = m / 80, mm = m - kk * 80, rr = mm / 5, t = mm - rr * 5;
        P[(size_t)(n0 + nbase + n) * 816 + 240 + kk * 144 + 9 * rr + t] = S[n * 321 + m];
      }
    }
  }
  __syncthreads();

  // ============== Phase D2: xd(32, ij=5..8) -> Pd slots ij>=5 (256) =========
  for (int idx = tid; idx < nrem * 128; idx += 256) {
    int n = idx >> 7, m = idx & 127, c = m >> 2, t = m & 3;
    S[n * 129 + m] = x_d[(size_t)(n0 + n) * 288 + c * 9 + 5 + t];
  }
  __syncthreads();
  {
    float acc[16][4];
    #pragma unroll
    for (int r = 0; r < 16; r++)
      #pragma unroll
      for (int t = 0; t < 4; t++) acc[r][t] = 0.0f;
    const float* xrow = &S[lane * 129];
    for (int c0 = 0; c0 < 32; c0 += 8) {
      float xr[8][4];
      #pragma unroll
      for (int j = 0; j < 8; j++)
        #pragma unroll
        for (int t = 0; t < 4; t++) xr[j][t] = xrow[(c0 + j) * 4 + t];
      #pragma unroll
      for (int r = 0; r < 16; r++) {
        const float* wp = W1_d + wu * 512 + r * 32 + c0;   // uniform, k = wu
        #pragma unroll
        for (int j = 0; j < 8; j++) {
          float w = wp[j];
          #pragma unroll
          for (int t = 0; t < 4; t++) acc[r][t] += w * xr[j][t];
        }
      }
    }
    #pragma unroll
    for (int h = 0; h < 2; h++) {
      __syncthreads();
      if ((lane >> 5) == h) {
        int l5 = lane & 31;
        #pragma unroll
        for (int r = 0; r < 16; r++)
          #pragma unroll
          for (int t = 0; t < 4; t++)
            S[l5 * 257 + wu * 64 + r * 4 + t] = acc[r][t];
      }
      __syncthreads();
      int nbase = h * 32;
      int cnt = min(nrem - nbase, 32);
      for (int u = tid; u < cnt * 256; u += 256) {
        int n = u >> 8, m = u & 255;
        int kk = m >> 6, mm = m & 63, rr = mm >> 2, t = mm & 3;
        P[(size_t)(n0 + nbase + n) * 816 + 240 + kk * 144 + 9 * rr + 5 + t] = S[n * 257 + m];
      }
    }
  }
}

// ------------------- CSR build ---------------------------------------------
__global__ void hist_kernel(const int* __restrict__ src, int* __restrict__ counts, int E) {
  int e = blockIdx.x * 256 + threadIdx.x;
  if (e < E) atomicAdd(&counts[src[e]], 1);
}

__global__ __launch_bounds__(1024) void scan_kernel(
    const int* __restrict__ counts, int* __restrict__ offs, int* __restrict__ cursor,
    int N, int E)
{
  __shared__ int part[1024];
  int tid = threadIdx.x;
  int chunk = (N + 1023) / 1024;
  int lo = tid * chunk, hi = min(lo + chunk, N);
  int s = 0;
  for (int i = lo; i < hi; i++) s += counts[i];
  part[tid] = s;
  __syncthreads();
  for (int off = 1; off < 1024; off <<= 1) {
    int v = (tid >= off) ? part[tid - off] : 0;
    __syncthreads();
    part[tid] += v;
    __syncthreads();
  }
  int run = part[tid] - s;  // exclusive prefix of this thread's chunk
  for (int i = lo; i < hi; i++) { offs[i] = run; cursor[i] = run; run += counts[i]; }
  if (tid == 0) offs[N] = E;
}

__global__ void scatter_kernel(const int* __restrict__ src, int* __restrict__ cursor,
                               int* __restrict__ eidx, int E) {
  int e = blockIdx.x * 256 + threadIdx.x;
  if (e < E) { int p = atomicAdd(&cursor[src[e]], 1); eidx[p] = e; }
}

// ------------------- K2: one wave per node, 4 nodes per block ---------------
// Each 256-thread block = 4 INDEPENDENT waves, one node each, wave-private
// 1280-float LDS slice. All sync points are wave-internal -> s_waitcnt
// lgkmcnt(0) replaces __syncthreads (no s_barrier, waves never couple).
// Per-wave LDS float map (1280):
//   [0,816)    sP  (gathered P[dst] for current edge)
//   [816,992)  sq  (q[i*16+r], 176)
//   [992,996)  rvtab: rv0,rv1,rv2,1.0
//   [996,1005) outer[ij] = rv_i*rv_j
//   [1008,1264) edge meta float4[64]: (r0,r1,r2, dst-as-float-bits)
// Epilogue reuses [0,960) as ACC:
//   [0,48) A_a[k*16+r]; [48,240) A_v[48+k*48+j*16+r];
//   [240,960) S[240 + s*180 + ij*20 + r]   (row stride 20 breaks bank aliasing)
__global__ __launch_bounds__(256, 6) void node_gather_kernel(
    const float* __restrict__ r_ij, const int* __restrict__ dst,
    const int* __restrict__ offs, const int* __restrict__ eidx,
    const float* __restrict__ Pg, const float* __restrict__ W2,
    const float* __restrict__ Wo_a, const float* __restrict__ Wo_v, const float* __restrict__ Wo_d,
    float* __restrict__ out, int N)
{
  __shared__ __align__(16) float Sall[5120];    // 4 x 1280
  const int wid = threadIdx.x >> 6;
  const int lane = threadIdx.x & 63;
  const int n = blockIdx.x * 4 + wid;
  if (n >= N) return;
  float* S = Sall + wid * 1280;
  float4* S4 = (float4*)S;
  const int off = offs[n], deg = offs[n + 1] - off;

  // ---- per-lane slot constants (V slots p=0..2, D slots p=3..11) ----
  int aP[12], aQ[12], aF[12];
  unsigned typm = 0;  // bit p set => dot3-with-rv form
  #pragma unroll
  for (int p = 0; p < 3; p++) {
    int t = lane + 64 * p;                 // < 192 always
    int k = t / 48, m = t - 48 * k, jj = m >> 4, r = m & 15;
    int q_ = 816 + (3 + k) * 16 + r;       // q3..q6
    int P_, F_;
    if (k == 0)      { P_ = 16 + r;              F_ = 992 + jj; }
    else if (k == 1) { P_ = 48 + 3 * r + jj;     F_ = 995; }
    else if (k == 2) { P_ = 192 + 3 * r;         F_ = 992 + jj; typm |= 1u << p; }
    else             { P_ = 384 + 9 * r + 3 * jj; F_ = 995;     typm |= 1u << p; }
    aP[p] = P_; aQ[p] = q_; aF[p] = F_;
  }
  #pragma unroll
  for (int p = 0; p < 9; p++) {
    int u = lane + 64 * p;                 // < 576 always
    int s = u / 144, m = u - 144 * s, ij = m >> 4, r = m & 15;
    int i = ij / 3, jj = ij - 3 * i;
    int P_, F_, q_;
    if (s == 0)      { P_ = 32 + r;              q_ = 112 + r; F_ = 996 + ij; }
    else if (s == 1) { P_ = 144 + 3 * r + i;     q_ = 128 + r; F_ = 992 + jj; }
    else if (s == 2) { P_ = 240 + 9 * r + ij;    q_ = 144 + r; F_ = 995; }
    else             { P_ = 672 + 9 * r + 3 * i; q_ = 160 + r; F_ = 992 + jj; typm |= 1u << (3 + p); }
    aP[3 + p] = P_; aQ[3 + p] = 816 + q_; aF[3 + p] = F_;
  }
  const int ak = lane >> 4, ar = lane & 15;   // A slot (lane<48)

  // ---- hoist W2 rows for this lane's q slots ----
  float4 wqa[3], wqb[3];
  #pragma unroll
  for (int p = 0; p < 3; p++) {
    int tq = lane + 64 * p; if (tq > 175) tq = 175;
    const float4* w = (const float4*)(W2 + tq * 8);
    wqa[p] = w[0]; wqb[p] = w[1];
  }

  float accA = 0.0f, acc[12];
  #pragma unroll
  for (int p = 0; p < 12; p++) acc[p] = 0.0f;

  float4 pb0 = {}, pb1 = {}, pb2 = {}, pb3 = {};
  const int l3 = 192 + (lane < 12 ? lane : 0);

  for (int base = 0; base < deg; base += 64) {
    int cnt = min(deg - base, 64);
    WAVE_SYNC();                       // prev chunk's meta reads drained
    if (lane < cnt) {
      int e = eidx[off + base + lane];
      float a = r_ij[3 * (size_t)e], b = r_ij[3 * (size_t)e + 1], c = r_ij[3 * (size_t)e + 2];
      S4[252 + lane] = make_float4(a, b, c, __int_as_float(dst[e]));
    }
    WAVE_SYNC();                       // meta visible to whole wave
    // preload edge 0 of this chunk
    {
      float4 me = S4[252];
      if (me.x * me.x + me.y * me.y + me.z * me.z < 5.0f) {
        const float4* Pp = (const float4*)(Pg + (size_t)__float_as_int(me.w) * 816);
        pb0 = Pp[lane]; pb1 = Pp[64 + lane]; pb2 = Pp[128 + lane]; pb3 = Pp[l3];
      }
    }
    for (int t = 0; t < cnt; t++) {
      float4 me = S4[252 + t];
      float r0 = me.x, r1 = me.y, r2 = me.z;
      float rr = r0 * r0 + r1 * r1 + r2 * r2;
      bool live = rr < 5.0f;
      float rv0 = 0, rv1 = 0, rv2 = 0;
      if (live) {
        float x_sq = rr * (1.0f / R0_F);
        float env = 1.0f - x_sq;
        // rv
        float v0 = r0 * (17.0f / R0_F), v1 = r1 * (17.0f / R0_F), v2 = r2 * (17.0f / R0_F);
        float nn = sqrtf(v0 * v0 + v1 * v1 + v2 * v2);
        float sig = 2.0f / (1.0f + __expf(-nn)) - 1.0f;
        float sc = sig / (nn + 1e-6f);
        rv0 = v0 * sc; rv1 = v1 * sc; rv2 = v2 * sc;
        // radial basis: cos(k*th)*env via Chebyshev
        float rad[8];
        {
          float c1 = __cosf(PI_F * sqrtf(x_sq));
          float two_c1 = 2.0f * c1, cm2 = 1.0f, cm1 = c1;
          rad[0] = env; rad[1] = c1 * env;
          #pragma unroll
          for (int k = 2; k < 8; k++) { float c = two_c1 * cm1 - cm2; rad[k] = c * env; cm2 = cm1; cm1 = c; }
        }
        float4 ra = make_float4(rad[0], rad[1], rad[2], rad[3]);
        float4 rb = make_float4(rad[4], rad[5], rad[6], rad[7]);
        // stage sP from prefetch regs
        S4[lane] = pb0; S4[64 + lane] = pb1; S4[128 + lane] = pb2;
        if (lane < 12) S4[192 + lane] = pb3;
        // q values
        S[816 + lane] = dot4(wqa[0], ra) + dot4(wqb[0], rb);
        S[880 + lane] = dot4(wqa[1], ra) + dot4(wqb[1], rb);
        if (lane < 48) S[944 + lane] = dot4(wqa[2], ra) + dot4(wqb[2], rb);
        // tables
        if (lane < 4) S[992 + lane] = (lane == 0) ? rv0 : (lane == 1) ? rv1 : (lane == 2) ? rv2 : 1.0f;
        if (lane >= 4 && lane < 13) {
          int ij = lane - 4, i = ij / 3, j = ij - 3 * i;
          float a = (i == 0) ? rv0 : (i == 1) ? rv1 : rv2;
          float b = (j == 0) ? rv0 : (j == 1) ? rv1 : rv2;
          S[992 + lane] = a * b;   // outer[ij] at 996+ij
        }
      }
      // prefetch next edge's P row (overlaps with accumulation)
      if (t + 1 < cnt) {
        float4 m2 = S4[252 + t + 1];
        if (m2.x * m2.x + m2.y * m2.y + m2.z * m2.z < 5.0f) {
          const float4* Pp = (const float4*)(Pg + (size_t)__float_as_int(m2.w) * 816);
          pb0 = Pp[lane]; pb1 = Pp[64 + lane]; pb2 = Pp[128 + lane]; pb3 = Pp[l3];
        }
      }
      WAVE_SYNC();                     // staged sP/q/tables visible
      if (live) {
        // A slot
        if (lane < 48) {
          float v;
          if (ak == 0)      v = S[ar] * S[816 + ar];
          else if (ak == 1) v = (S[96 + 3 * ar] * rv0 + S[97 + 3 * ar] * rv1 + S[98 + 3 * ar] * rv2) * S[832 + ar];
          else {
            int b = 528 + 9 * ar;
            float o = (S[b] * rv0 + S[b + 3] * rv1 + S[b + 6] * rv2) * rv0
                    + (S[b + 1] * rv0 + S[b + 4] * rv1 + S[b + 7] * rv2) * rv1
                    + (S[b + 2] * rv0 + S[b + 5] * rv1 + S[b + 8] * rv2) * rv2;
            v = o * S[848 + ar];
          }
          accA += v;
        }
        // V + D slots, unified form
        #pragma unroll
        for (int p = 0; p < 12; p++) {
          float pv;
          if (typm & (1u << p)) pv = S[aP[p]] * rv0 + S[aP[p] + 1] * rv1 + S[aP[p] + 2] * rv2;
          else                  pv = S[aP[p]];
          acc[p] += pv * S[aQ[p]] * S[aF[p]];
        }
      }
      WAVE_SYNC();                     // reads drained before next t's writes
    }
  }

  // ---------------- epilogue: rank->channel, write out ----------------
  WAVE_SYNC();
  if (lane < 48) S[lane] = accA;
  #pragma unroll
  for (int p = 0; p < 3; p++) S[48 + lane + 64 * p] = acc[p];
  #pragma unroll
  for (int p = 0; p < 9; p++) {
    int u = lane + 64 * p;
    int s = u / 144, m = u - 144 * s, ij = m >> 4, r = m & 15;
    S[240 + s * 180 + ij * 20 + r] = acc[3 + p];
  }
  WAVE_SYNC();

  const size_t baseV = (size_t)N * 128;
  const size_t baseD = (size_t)N * 320;

  // B_a
  #pragma unroll
  for (int h = 0; h < 2; h++) {
    int c = lane + 64 * h;
    float a_ = 0.0f;
    #pragma unroll
    for (int k = 0; k < 3; k++) {
      const float4* w = (const float4*)(Wo_a + k * 2048 + c * 16);
      const float4* A4 = (const float4*)(&S[k * 16]);
      #pragma unroll
      for (int cc = 0; cc < 4; cc++) a_ += dot4(w[cc], A4[cc]);
    }
    out[(size_t)n * 128 + c] = a_;
  }
  // B_v (d = lane)
  {
    float o0 = 0, o1 = 0, o2 = 0;
    #pragma unroll
    for (int k = 0; k < 4; k++) {
      const float4* w = (const float4*)(Wo_v + k * 1024 + lane * 16);
      float4 w0 = w[0], w1 = w[1], w2 = w[2], w3 = w[3];
      #pragma unroll
      for (int j = 0; j < 3; j++) {
        const float4* A4 = (const float4*)(&S[48 + k * 48 + j * 16]);
        float v = dot4(w0, A4[0]) + dot4(w1, A4[1]) + dot4(w2, A4[2]) + dot4(w3, A4[3]);
        if (j == 0) o0 += v; else if (j == 1) o1 += v; else o2 += v;
      }
    }
    size_t ov = baseV + (size_t)n * 192 + lane * 3;
    out[ov] = o0; out[ov + 1] = o1; out[ov + 2] = o2;
  }
  // B_d
  #pragma unroll
  for (int p = 0; p < 5; p++) {
    int t = lane + 64 * p;
    if (t < 288) {
      int d = t / 9, ij = t - 9 * d;
      float a_ = 0.0f;
      #pragma unroll
      for (int s = 0; s < 4; s++) {
        const float4* w = (const float4*)(Wo_d + s * 512 + d * 16);
        const float4* A4 = (const float4*)(&S[240 + s * 180 + ij * 20]);
        a_ += dot4(w[0], A4[0]) + dot4(w[1], A4[1]) + dot4(w[2], A4[2]) + dot4(w[3], A4[3]);
      }
      out[baseD + (size_t)n * 288 + t] = a_;
    }
  }
}

// ---------------------------------------------------------------------------
extern "C" void kernel_launch(void* const* d_in, const int* in_sizes, int n_in,
                              void* d_out, int out_size, void* d_ws, size_t ws_size,
                              hipStream_t stream) {
  const float* r_ij = (const float*)d_in[0];
  const float* x_a  = (const float*)d_in[1];
  const float* x_v  = (const float*)d_in[2];
  const float* x_d  = (const float*)d_in[3];
  const float* W1_a = (const float*)d_in[4];
  const float* W1_v = (const float*)d_in[5];
  const float* W1_d = (const float*)d_in[6];
  const float* W2   = (const float*)d_in[7];
  const float* Wo_a = (const float*)d_in[8];
  const float* Wo_v = (const float*)d_in[9];
  const float* Wo_d = (const float*)d_in[10];
  const int*  src   = (const int*)d_in[11];
  const int*  dst   = (const int*)d_in[12];

  const int E = in_sizes[0] / 3;
  const int N = in_sizes[1] / 128;

  float* P    = (float*)d_ws;
  int* counts = (int*)(P + (size_t)N * 816);
  int* offs   = counts + N;
  int* cursor = offs + N + 1;
  int* eidx   = cursor + N;

  hipMemsetAsync(counts, 0, sizeof(int) * (size_t)N, stream);

  hist_kernel<<<(E + 255) / 256, 256, 0, stream>>>(src, counts, E);
  scan_kernel<<<1, 1024, 0, stream>>>(counts, offs, cursor, N, E);
  scatter_kernel<<<(E + 255) / 256, 256, 0, stream>>>(src, cursor, eidx, E);
  node_proj_kernel<<<(N + 63) / 64, 256, 0, stream>>>(x_a, x_v, x_d, W1_a, W1_v, W1_d, P, N);
  node_gather_kernel<<<(N + 3) / 4, 256, 0, stream>>>(r_ij, dst, offs, eidx, P, W2,
                                                      Wo_a, Wo_v, Wo_d, (float*)d_out, N);
}

// Round 3
// 1054.477 us; speedup vs baseline: 1.5546x; 1.5546x over previous
//
#include <hip/hip_runtime.h>
#include <hip/hip_bf16.h>
#include <math.h>

#define PI_F 3.14159265358979323846f
#define R0_F 5.0f

// ---------------------------------------------------------------------------
// ws layout:
//   P[n][816] float : per-node input projections
//     [0,48)    Pa[k*16+r]                 k=0:pa000,1:pa011,2:pa022
//     [48,240)  Pv[48+k*48+3r+i]           k=0:pv101,1:pv110,2:pv112,3:pv121
//     [240,816) Pd[240+k*144+9r+ij]        k=0:pd202,1:pd211,2:pd220,3:pd222
//   counts[N] | offs[N+1] | cursor[N] | eidx[E]   (ints, CSR by src)
// ---------------------------------------------------------------------------

static __device__ __forceinline__ float dot4(float4 a, float4 b) {
  return a.x * b.x + a.y * b.y + a.z * b.z + a.w * b.w;
}

// ------------------- K1: per-node input projections (v2) --------------------
__global__ __launch_bounds__(256) void node_proj_kernel(
    const float* __restrict__ x_a, const float* __restrict__ x_v, const float* __restrict__ x_d,
    const float* __restrict__ W1_a, const float* __restrict__ W1_v, const float* __restrict__ W1_d,
    float* __restrict__ P, int N)
{
  __shared__ float S[12352];           // 48.25 KB, reused each phase
  const int tid = threadIdx.x;
  const int lane = tid & 63;
  const int wu = __builtin_amdgcn_readfirstlane(tid >> 6);  // uniform wave id 0..3
  const int n0 = blockIdx.x * 64;
  const int nrem = min(N - n0, 64);    // valid nodes in this block

  // ===================== Phase A: xa(128) -> Pa (48 slots) ==================
  for (int idx4 = tid; idx4 < nrem * 32; idx4 += 256) {
    int n = idx4 >> 5, c4 = idx4 & 31;
    float4 v = ((const float4*)(x_a + (size_t)(n0 + n) * 128))[c4];
    float* d = &S[n * 129 + c4 * 4];
    d[0] = v.x; d[1] = v.y; d[2] = v.z; d[3] = v.w;
  }
  __syncthreads();
  {
    float acc[12];
    #pragma unroll
    for (int q = 0; q < 12; q++) acc[q] = 0.0f;
    const float* xrow = &S[lane * 129];
    for (int c0 = 0; c0 < 128; c0 += 16) {
      float xr[16];
      #pragma unroll
      for (int j = 0; j < 16; j++) xr[j] = xrow[c0 + j];
      #pragma unroll
      for (int q = 0; q < 12; q++) {
        int o = wu * 12 + q;                       // uniform: slot = k*16+r = o
        const float* wp = W1_a + (o >> 4) * 2048 + (o & 15) * 128 + c0;
        float s = 0.0f;
        #pragma unroll
        for (int j = 0; j < 16; j++) s += wp[j] * xr[j];
        acc[q] += s;
      }
    }
    __syncthreads();
    #pragma unroll
    for (int q = 0; q < 12; q++) S[lane * 49 + wu * 12 + q] = acc[q];
    __syncthreads();
    for (int u = tid; u < nrem * 12; u += 256) {
      int n = u / 12, m4 = u - n * 12;
      const float* s = &S[n * 49 + m4 * 4];
      ((float4*)(P + (size_t)(n0 + n) * 816))[m4] = make_float4(s[0], s[1], s[2], s[3]);
    }
  }
  __syncthreads();

  // ===================== Phase V: xv(64,3) -> Pv (192 slots) ================
  for (int idx4 = tid; idx4 < nrem * 48; idx4 += 256) {
    int n = idx4 / 48, m4 = idx4 - n * 48;
    float4 v = ((const float4*)(x_v + (size_t)(n0 + n) * 192))[m4];
    float* d = &S[n * 193 + m4 * 4];
    d[0] = v.x; d[1] = v.y; d[2] = v.z; d[3] = v.w;
  }
  __syncthreads();
  {
    float acc[16][3];
    #pragma unroll
    for (int r = 0; r < 16; r++)
      #pragma unroll
      for (int i = 0; i < 3; i++) acc[r][i] = 0.0f;
    const float* xrow = &S[lane * 193];
    for (int c0 = 0; c0 < 64; c0 += 16) {
      float xr[16][3];
      #pragma unroll
      for (int j = 0; j < 16; j++) {
        xr[j][0] = xrow[(c0 + j) * 3 + 0];
        xr[j][1] = xrow[(c0 + j) * 3 + 1];
        xr[j][2] = xrow[(c0 + j) * 3 + 2];
      }
      #pragma unroll
      for (int r = 0; r < 16; r++) {
        const float* wp = W1_v + wu * 1024 + r * 64 + c0;  // uniform, k = wu
        #pragma unroll
        for (int j = 0; j < 16; j++) {
          float w = wp[j];
          acc[r][0] += w * xr[j][0];
          acc[r][1] += w * xr[j][1];
          acc[r][2] += w * xr[j][2];
        }
      }
    }
    __syncthreads();
    #pragma unroll
    for (int r = 0; r < 16; r++)
      #pragma unroll
      for (int i = 0; i < 3; i++)
        S[lane * 193 + wu * 48 + r * 3 + i] = acc[r][i];
    __syncthreads();
    for (int u = tid; u < nrem * 48; u += 256) {
      int n = u / 48, m4 = u - n * 48;
      const float* s = &S[n * 193 + m4 * 4];
      ((float4*)(P + (size_t)(n0 + n) * 816 + 48))[m4] = make_float4(s[0], s[1], s[2], s[3]);
    }
  }
  __syncthreads();

  // ============== Phase D1: xd(32, ij=0..4) -> Pd slots ij<5 (320) ==========
  for (int idx = tid; idx < nrem * 160; idx += 256) {
    int n = idx / 160, m = idx - n * 160, c = m / 5, ij = m - c * 5;
    S[n * 161 + m] = x_d[(size_t)(n0 + n) * 288 + c * 9 + ij];
  }
  __syncthreads();
  {
    float acc[16][5];
    #pragma unroll
    for (int r = 0; r < 16; r++)
      #pragma unroll
      for (int t = 0; t < 5; t++) acc[r][t] = 0.0f;
    const float* xrow = &S[lane * 161];
    for (int c0 = 0; c0 < 32; c0 += 8) {
      float xr[8][5];
      #pragma unroll
      for (int j = 0; j < 8; j++)
        #pragma unroll
        for (int t = 0; t < 5; t++) xr[j][t] = xrow[(c0 + j) * 5 + t];
      #pragma unroll
      for (int r = 0; r < 16; r++) {
        const float* wp = W1_d + wu * 512 + r * 32 + c0;   // uniform, k = wu
        #pragma unroll
        for (int j = 0; j < 8; j++) {
          float w = wp[j];
          #pragma unroll
          for (int t = 0; t < 5; t++) acc[r][t] += w * xr[j][t];
        }
      }
    }
    #pragma unroll
    for (int h = 0; h < 2; h++) {
      __syncthreads();
      if ((lane >> 5) == h) {
        int l5 = lane & 31;
        #pragma unroll
        for (int r = 0; r < 16; r++)
          #pragma unroll
          for (int t = 0; t < 5; t++)
            S[l5 * 321 + wu * 80 + r * 5 + t] = acc[r][t];
      }
      __syncthreads();
      int nbase = h * 32;
      int cnt = min(nrem - nbase, 32);
      for (int u = tid; u < cnt * 320; u += 256) {
        int n = u / 320, m = u - n * 320;
        int kk = m / 80, mm = m - kk * 80, rr = mm / 5, t = mm - rr * 5;
        P[(size_t)(n0 + nbase + n) * 816 + 240 + kk * 144 + 9 * rr + t] = S[n * 321 + m];
      }
    }
  }
  __syncthreads();

  // ============== Phase D2: xd(32, ij=5..8) -> Pd slots ij>=5 (256) =========
  for (int idx = tid; idx < nrem * 128; idx += 256) {
    int n = idx >> 7, m = idx & 127, c = m >> 2, t = m & 3;
    S[n * 129 + m] = x_d[(size_t)(n0 + n) * 288 + c * 9 + 5 + t];
  }
  __syncthreads();
  {
    float acc[16][4];
    #pragma unroll
    for (int r = 0; r < 16; r++)
      #pragma unroll
      for (int t = 0; t < 4; t++) acc[r][t] = 0.0f;
    const float* xrow = &S[lane * 129];
    for (int c0 = 0; c0 < 32; c0 += 8) {
      float xr[8][4];
      #pragma unroll
      for (int j = 0; j < 8; j++)
        #pragma unroll
        for (int t = 0; t < 4; t++) xr[j][t] = xrow[(c0 + j) * 4 + t];
      #pragma unroll
      for (int r = 0; r < 16; r++) {
        const float* wp = W1_d + wu * 512 + r * 32 + c0;   // uniform, k = wu
        #pragma unroll
        for (int j = 0; j < 8; j++) {
          float w = wp[j];
          #pragma unroll
          for (int t = 0; t < 4; t++) acc[r][t] += w * xr[j][t];
        }
      }
    }
    #pragma unroll
    for (int h = 0; h < 2; h++) {
      __syncthreads();
      if ((lane >> 5) == h) {
        int l5 = lane & 31;
        #pragma unroll
        for (int r = 0; r < 16; r++)
          #pragma unroll
          for (int t = 0; t < 4; t++)
            S[l5 * 257 + wu * 64 + r * 4 + t] = acc[r][t];
      }
      __syncthreads();
      int nbase = h * 32;
      int cnt = min(nrem - nbase, 32);
      for (int u = tid; u < cnt * 256; u += 256) {
        int n = u >> 8, m = u & 255;
        int kk = m >> 6, mm = m & 63, rr = mm >> 2, t = mm & 3;
        P[(size_t)(n0 + nbase + n) * 816 + 240 + kk * 144 + 9 * rr + 5 + t] = S[n * 257 + m];
      }
    }
  }
}

// ------------------- CSR build ---------------------------------------------
__global__ void hist_kernel(const int* __restrict__ src, int* __restrict__ counts, int E) {
  int e = blockIdx.x * 256 + threadIdx.x;
  if (e < E) atomicAdd(&counts[src[e]], 1);
}

__global__ __launch_bounds__(1024) void scan_kernel(
    const int* __restrict__ counts, int* __restrict__ offs, int* __restrict__ cursor,
    int N, int E)
{
  __shared__ int part[1024];
  int tid = threadIdx.x;
  int chunk = (N + 1023) / 1024;
  int lo = tid * chunk, hi = min(lo + chunk, N);
  int s = 0;
  for (int i = lo; i < hi; i++) s += counts[i];
  part[tid] = s;
  __syncthreads();
  for (int off = 1; off < 1024; off <<= 1) {
    int v = (tid >= off) ? part[tid - off] : 0;
    __syncthreads();
    part[tid] += v;
    __syncthreads();
  }
  int run = part[tid] - s;  // exclusive prefix of this thread's chunk
  for (int i = lo; i < hi; i++) { offs[i] = run; cursor[i] = run; run += counts[i]; }
  if (tid == 0) offs[N] = E;
}

__global__ void scatter_kernel(const int* __restrict__ src, int* __restrict__ cursor,
                               int* __restrict__ eidx, int E) {
  int e = blockIdx.x * 256 + threadIdx.x;
  if (e < E) { int p = atomicAdd(&cursor[src[e]], 1); eidx[p] = e; }
}

// ------------------- K2: 4 nodes per block (1 wave each), barrier-uniform ---
// Each 256-thread block = 4 waves, one node each, wave-private 1280-float LDS
// slice. Barriers are __syncthreads(); to keep trip counts uniform across the
// 4 waves, ALL waves loop to degmax = max(deg of the 4 nodes) and mask dead
// iterations with `live`. A dead iteration costs 2 barriers (~tens of cycles)
// vs ~450 cycles for a live edge: ~4% overhead for ~2x occupancy.
// Per-wave LDS float map (1280):
//   [0,816)    sP  (gathered P[dst] for current edge)
//   [816,992)  sq  (q[i*16+r], 176)
//   [992,996)  rvtab: rv0,rv1,rv2,1.0
//   [996,1005) outer[ij] = rv_i*rv_j
//   [1008,1264) edge meta float4[64]: (r0,r1,r2, dst-as-float-bits)
// Epilogue reuses [0,960) as ACC:
//   [0,48) A_a[k*16+r]; [48,240) A_v[48+k*48+j*16+r];
//   [240,960) S[240 + s*180 + ij*20 + r]   (row stride 20 breaks bank aliasing)
__global__ __launch_bounds__(256, 5) void node_gather_kernel(
    const float* __restrict__ r_ij, const int* __restrict__ dst,
    const int* __restrict__ offs, const int* __restrict__ eidx,
    const float* __restrict__ Pg, const float* __restrict__ W2,
    const float* __restrict__ Wo_a, const float* __restrict__ Wo_v, const float* __restrict__ Wo_d,
    float* __restrict__ out, int N)
{
  __shared__ __align__(16) float Sall[5120];    // 4 x 1280
  __shared__ int degs[4];
  const int wid = threadIdx.x >> 6;
  const int lane = threadIdx.x & 63;
  const int n = blockIdx.x * 4 + wid;
  const bool valid = (n < N);
  float* S = Sall + wid * 1280;
  float4* S4 = (float4*)S;
  const int off = valid ? offs[n] : 0;
  const int deg = valid ? (offs[n + 1] - off) : 0;
  if (lane == 0) degs[wid] = deg;

  // ---- per-lane slot constants (V slots p=0..2, D slots p=3..11) ----
  int aP[12], aQ[12], aF[12];
  unsigned typm = 0;  // bit p set => dot3-with-rv form
  #pragma unroll
  for (int p = 0; p < 3; p++) {
    int t = lane + 64 * p;                 // < 192 always
    int k = t / 48, m = t - 48 * k, jj = m >> 4, r = m & 15;
    int q_ = 816 + (3 + k) * 16 + r;       // q3..q6
    int P_, F_;
    if (k == 0)      { P_ = 16 + r;              F_ = 992 + jj; }
    else if (k == 1) { P_ = 48 + 3 * r + jj;     F_ = 995; }
    else if (k == 2) { P_ = 192 + 3 * r;         F_ = 992 + jj; typm |= 1u << p; }
    else             { P_ = 384 + 9 * r + 3 * jj; F_ = 995;     typm |= 1u << p; }
    aP[p] = P_; aQ[p] = q_; aF[p] = F_;
  }
  #pragma unroll
  for (int p = 0; p < 9; p++) {
    int u = lane + 64 * p;                 // < 576 always
    int s = u / 144, m = u - 144 * s, ij = m >> 4, r = m & 15;
    int i = ij / 3, jj = ij - 3 * i;
    int P_, F_, q_;
    if (s == 0)      { P_ = 32 + r;              q_ = 112 + r; F_ = 996 + ij; }
    else if (s == 1) { P_ = 144 + 3 * r + i;     q_ = 128 + r; F_ = 992 + jj; }
    else if (s == 2) { P_ = 240 + 9 * r + ij;    q_ = 144 + r; F_ = 995; }
    else             { P_ = 672 + 9 * r + 3 * i; q_ = 160 + r; F_ = 992 + jj; typm |= 1u << (3 + p); }
    aP[3 + p] = P_; aQ[3 + p] = 816 + q_; aF[3 + p] = F_;
  }
  const int ak = lane >> 4, ar = lane & 15;   // A slot (lane<48)

  // ---- hoist W2 rows for this lane's q slots ----
  float4 wqa[3], wqb[3];
  #pragma unroll
  for (int p = 0; p < 3; p++) {
    int tq = lane + 64 * p; if (tq > 175) tq = 175;
    const float4* w = (const float4*)(W2 + tq * 8);
    wqa[p] = w[0]; wqb[p] = w[1];
  }

  float accA = 0.0f, acc[12];
  #pragma unroll
  for (int p = 0; p < 12; p++) acc[p] = 0.0f;

  float4 pb0 = {}, pb1 = {}, pb2 = {}, pb3 = {};
  const int l3 = 192 + (lane < 12 ? lane : 0);

  __syncthreads();
  const int degmax = max(max(degs[0], degs[1]), max(degs[2], degs[3]));

  for (int base = 0; base < degmax; base += 64) {
    const int cnt = min(max(deg - base, 0), 64);      // this wave's live edges
    const int cntmax = min(degmax - base, 64);        // uniform trip count
    __syncthreads();
    if (lane < cnt) {
      int e = eidx[off + base + lane];
      float a = r_ij[3 * (size_t)e], b = r_ij[3 * (size_t)e + 1], c = r_ij[3 * (size_t)e + 2];
      S4[252 + lane] = make_float4(a, b, c, __int_as_float(dst[e]));
    }
    __syncthreads();
    // preload edge 0 of this chunk
    if (cnt > 0) {
      float4 me = S4[252];
      if (me.x * me.x + me.y * me.y + me.z * me.z < 5.0f) {
        const float4* Pp = (const float4*)(Pg + (size_t)__float_as_int(me.w) * 816);
        pb0 = Pp[lane]; pb1 = Pp[64 + lane]; pb2 = Pp[128 + lane]; pb3 = Pp[l3];
      }
    }
    for (int t = 0; t < cntmax; t++) {
      float4 me = S4[252 + t];
      float r0 = me.x, r1 = me.y, r2 = me.z;
      float rr = r0 * r0 + r1 * r1 + r2 * r2;
      bool live = (t < cnt) && (rr < 5.0f);
      float rv0 = 0, rv1 = 0, rv2 = 0;
      if (live) {
        float x_sq = rr * (1.0f / R0_F);
        float env = 1.0f - x_sq;
        // rv
        float v0 = r0 * (17.0f / R0_F), v1 = r1 * (17.0f / R0_F), v2 = r2 * (17.0f / R0_F);
        float nn = sqrtf(v0 * v0 + v1 * v1 + v2 * v2);
        float sig = 2.0f / (1.0f + __expf(-nn)) - 1.0f;
        float sc = sig / (nn + 1e-6f);
        rv0 = v0 * sc; rv1 = v1 * sc; rv2 = v2 * sc;
        // radial basis: cos(k*th)*env via Chebyshev
        float rad[8];
        {
          float c1 = __cosf(PI_F * sqrtf(x_sq));
          float two_c1 = 2.0f * c1, cm2 = 1.0f, cm1 = c1;
          rad[0] = env; rad[1] = c1 * env;
          #pragma unroll
          for (int k = 2; k < 8; k++) { float c = two_c1 * cm1 - cm2; rad[k] = c * env; cm2 = cm1; cm1 = c; }
        }
        float4 ra = make_float4(rad[0], rad[1], rad[2], rad[3]);
        float4 rb = make_float4(rad[4], rad[5], rad[6], rad[7]);
        // stage sP from prefetch regs
        S4[lane] = pb0; S4[64 + lane] = pb1; S4[128 + lane] = pb2;
        if (lane < 12) S4[192 + lane] = pb3;
        // q values
        S[816 + lane] = dot4(wqa[0], ra) + dot4(wqb[0], rb);
        S[880 + lane] = dot4(wqa[1], ra) + dot4(wqb[1], rb);
        if (lane < 48) S[944 + lane] = dot4(wqa[2], ra) + dot4(wqb[2], rb);
        // tables
        if (lane < 4) S[992 + lane] = (lane == 0) ? rv0 : (lane == 1) ? rv1 : (lane == 2) ? rv2 : 1.0f;
        if (lane >= 4 && lane < 13) {
          int ij = lane - 4, i = ij / 3, j = ij - 3 * i;
          float a = (i == 0) ? rv0 : (i == 1) ? rv1 : rv2;
          float b = (j == 0) ? rv0 : (j == 1) ? rv1 : rv2;
          S[992 + lane] = a * b;   // outer[ij] at 996+ij
        }
      }
      // prefetch next edge's P row (overlaps with accumulation)
      if (t + 1 < cnt) {
        float4 m2 = S4[252 + t + 1];
        if (m2.x * m2.x + m2.y * m2.y + m2.z * m2.z < 5.0f) {
          const float4* Pp = (const float4*)(Pg + (size_t)__float_as_int(m2.w) * 816);
          pb0 = Pp[lane]; pb1 = Pp[64 + lane]; pb2 = Pp[128 + lane]; pb3 = Pp[l3];
        }
      }
      __syncthreads();
      if (live) {
        // A slot
        if (lane < 48) {
          float v;
          if (ak == 0)      v = S[ar] * S[816 + ar];
          else if (ak == 1) v = (S[96 + 3 * ar] * rv0 + S[97 + 3 * ar] * rv1 + S[98 + 3 * ar] * rv2) * S[832 + ar];
          else {
            int b = 528 + 9 * ar;
            float o = (S[b] * rv0 + S[b + 3] * rv1 + S[b + 6] * rv2) * rv0
                    + (S[b + 1] * rv0 + S[b + 4] * rv1 + S[b + 7] * rv2) * rv1
                    + (S[b + 2] * rv0 + S[b + 5] * rv1 + S[b + 8] * rv2) * rv2;
            v = o * S[848 + ar];
          }
          accA += v;
        }
        // V + D slots, unified form
        #pragma unroll
        for (int p = 0; p < 12; p++) {
          float pv;
          if (typm & (1u << p)) pv = S[aP[p]] * rv0 + S[aP[p] + 1] * rv1 + S[aP[p] + 2] * rv2;
          else                  pv = S[aP[p]];
          acc[p] += pv * S[aQ[p]] * S[aF[p]];
        }
      }
      __syncthreads();
    }
  }

  // ---------------- epilogue: rank->channel, write out ----------------
  __syncthreads();
  if (lane < 48) S[lane] = accA;
  #pragma unroll
  for (int p = 0; p < 3; p++) S[48 + lane + 64 * p] = acc[p];
  #pragma unroll
  for (int p = 0; p < 9; p++) {
    int u = lane + 64 * p;
    int s = u / 144, m = u - 144 * s, ij = m >> 4, r = m & 15;
    S[240 + s * 180 + ij * 20 + r] = acc[3 + p];
  }
  __syncthreads();

  if (valid) {
    const size_t baseV = (size_t)N * 128;
    const size_t baseD = (size_t)N * 320;

    // B_a
    #pragma unroll
    for (int h = 0; h < 2; h++) {
      int c = lane + 64 * h;
      float a_ = 0.0f;
      #pragma unroll
      for (int k = 0; k < 3; k++) {
        const float4* w = (const float4*)(Wo_a + k * 2048 + c * 16);
        const float4* A4 = (const float4*)(&S[k * 16]);
        #pragma unroll
        for (int cc = 0; cc < 4; cc++) a_ += dot4(w[cc], A4[cc]);
      }
      out[(size_t)n * 128 + c] = a_;
    }
    // B_v (d = lane)
    {
      float o0 = 0, o1 = 0, o2 = 0;
      #pragma unroll
      for (int k = 0; k < 4; k++) {
        const float4* w = (const float4*)(Wo_v + k * 1024 + lane * 16);
        float4 w0 = w[0], w1 = w[1], w2 = w[2], w3 = w[3];
        #pragma unroll
        for (int j = 0; j < 3; j++) {
          const float4* A4 = (const float4*)(&S[48 + k * 48 + j * 16]);
          float v = dot4(w0, A4[0]) + dot4(w1, A4[1]) + dot4(w2, A4[2]) + dot4(w3, A4[3]);
          if (j == 0) o0 += v; else if (j == 1) o1 += v; else o2 += v;
        }
      }
      size_t ov = baseV + (size_t)n * 192 + lane * 3;
      out[ov] = o0; out[ov + 1] = o1; out[ov + 2] = o2;
    }
    // B_d
    #pragma unroll
    for (int p = 0; p < 5; p++) {
      int t = lane + 64 * p;
      if (t < 288) {
        int d = t / 9, ij = t - 9 * d;
        float a_ = 0.0f;
        #pragma unroll
        for (int s = 0; s < 4; s++) {
          const float4* w = (const float4*)(Wo_d + s * 512 + d * 16);
          const float4* A4 = (const float4*)(&S[240 + s * 180 + ij * 20]);
          a_ += dot4(w[0], A4[0]) + dot4(w[1], A4[1]) + dot4(w[2], A4[2]) + dot4(w[3], A4[3]);
        }
        out[baseD + (size_t)n * 288 + t] = a_;
      }
    }
  }
}

// ---------------------------------------------------------------------------
extern "C" void kernel_launch(void* const* d_in, const int* in_sizes, int n_in,
                              void* d_out, int out_size, void* d_ws, size_t ws_size,
                              hipStream_t stream) {
  const float* r_ij = (const float*)d_in[0];
  const float* x_a  = (const float*)d_in[1];
  const float* x_v  = (const float*)d_in[2];
  const float* x_d  = (const float*)d_in[3];
  const float* W1_a = (const float*)d_in[4];
  const float* W1_v = (const float*)d_in[5];
  const float* W1_d = (const float*)d_in[6];
  const float* W2   = (const float*)d_in[7];
  const float* Wo_a = (const float*)d_in[8];
  const float* Wo_v = (const float*)d_in[9];
  const float* Wo_d = (const float*)d_in[10];
  const int*  src   = (const int*)d_in[11];
  const int*  dst   = (const int*)d_in[12];

  const int E = in_sizes[0] / 3;
  const int N = in_sizes[1] / 128;

  float* P    = (float*)d_ws;
  int* counts = (int*)(P + (size_t)N * 816);
  int* offs   = counts + N;
  int* cursor = offs + N + 1;
  int* eidx   = cursor + N;

  hipMemsetAsync(counts, 0, sizeof(int) * (size_t)N, stream);

  hist_kernel<<<(E + 255) / 256, 256, 0, stream>>>(src, counts, E);
  scan_kernel<<<1, 1024, 0, stream>>>(counts, offs, cursor, N, E);
  scatter_kernel<<<(E + 255) / 256, 256, 0, stream>>>(src, cursor, eidx, E);
  node_proj_kernel<<<(N + 63) / 64, 256, 0, stream>>>(x_a, x_v, x_d, W1_a, W1_v, W1_d, P, N);
  node_gather_kernel<<<(N + 3) / 4, 256, 0, stream>>>(r_ij, dst, offs, eidx, P, W2,
                                                      Wo_a, Wo_v, Wo_d, (float*)d_out, N);
}

// Round 4
// 516.546 us; speedup vs baseline: 3.1736x; 2.0414x over previous
//
#include <hip/hip_runtime.h>
#include <hip/hip_bf16.h>
#include <math.h>

#define PI_F 3.14159265358979323846f
#define R0_F 5.0f

// ---------------------------------------------------------------------------
// ws layout:
//   P[n][816] float : per-node input projections
//     [0,48)    Pa[k*16+r]                 k=0:pa000,1:pa011,2:pa022
//     [48,240)  Pv[48+k*48+3r+i]           k=0:pv101,1:pv110,2:pv112,3:pv121
//     [240,816) Pd[240+k*144+9r+ij]        k=0:pd202,1:pd211,2:pd220,3:pd222
//   counts[N] | offs[N+1] | cursor[N] | eidx[E]   (ints, CSR by src)
// ---------------------------------------------------------------------------

static __device__ __forceinline__ float dot4(float4 a, float4 b) {
  return a.x * b.x + a.y * b.y + a.z * b.z + a.w * b.w;
}

// ------------------- K1: per-node input projections (v2) --------------------
__global__ __launch_bounds__(256) void node_proj_kernel(
    const float* __restrict__ x_a, const float* __restrict__ x_v, const float* __restrict__ x_d,
    const float* __restrict__ W1_a, const float* __restrict__ W1_v, const float* __restrict__ W1_d,
    float* __restrict__ P, int N)
{
  __shared__ float S[12352];           // 48.25 KB, reused each phase
  const int tid = threadIdx.x;
  const int lane = tid & 63;
  const int wu = __builtin_amdgcn_readfirstlane(tid >> 6);  // uniform wave id 0..3
  const int n0 = blockIdx.x * 64;
  const int nrem = min(N - n0, 64);    // valid nodes in this block

  // ===================== Phase A: xa(128) -> Pa (48 slots) ==================
  for (int idx4 = tid; idx4 < nrem * 32; idx4 += 256) {
    int n = idx4 >> 5, c4 = idx4 & 31;
    float4 v = ((const float4*)(x_a + (size_t)(n0 + n) * 128))[c4];
    float* d = &S[n * 129 + c4 * 4];
    d[0] = v.x; d[1] = v.y; d[2] = v.z; d[3] = v.w;
  }
  __syncthreads();
  {
    float acc[12];
    #pragma unroll
    for (int q = 0; q < 12; q++) acc[q] = 0.0f;
    const float* xrow = &S[lane * 129];
    for (int c0 = 0; c0 < 128; c0 += 16) {
      float xr[16];
      #pragma unroll
      for (int j = 0; j < 16; j++) xr[j] = xrow[c0 + j];
      #pragma unroll
      for (int q = 0; q < 12; q++) {
        int o = wu * 12 + q;                       // uniform: slot = k*16+r = o
        const float* wp = W1_a + (o >> 4) * 2048 + (o & 15) * 128 + c0;
        float s = 0.0f;
        #pragma unroll
        for (int j = 0; j < 16; j++) s += wp[j] * xr[j];
        acc[q] += s;
      }
    }
    __syncthreads();
    #pragma unroll
    for (int q = 0; q < 12; q++) S[lane * 49 + wu * 12 + q] = acc[q];
    __syncthreads();
    for (int u = tid; u < nrem * 12; u += 256) {
      int n = u / 12, m4 = u - n * 12;
      const float* s = &S[n * 49 + m4 * 4];
      ((float4*)(P + (size_t)(n0 + n) * 816))[m4] = make_float4(s[0], s[1], s[2], s[3]);
    }
  }
  __syncthreads();

  // ===================== Phase V: xv(64,3) -> Pv (192 slots) ================
  for (int idx4 = tid; idx4 < nrem * 48; idx4 += 256) {
    int n = idx4 / 48, m4 = idx4 - n * 48;
    float4 v = ((const float4*)(x_v + (size_t)(n0 + n) * 192))[m4];
    float* d = &S[n * 193 + m4 * 4];
    d[0] = v.x; d[1] = v.y; d[2] = v.z; d[3] = v.w;
  }
  __syncthreads();
  {
    float acc[16][3];
    #pragma unroll
    for (int r = 0; r < 16; r++)
      #pragma unroll
      for (int i = 0; i < 3; i++) acc[r][i] = 0.0f;
    const float* xrow = &S[lane * 193];
    for (int c0 = 0; c0 < 64; c0 += 16) {
      float xr[16][3];
      #pragma unroll
      for (int j = 0; j < 16; j++) {
        xr[j][0] = xrow[(c0 + j) * 3 + 0];
        xr[j][1] = xrow[(c0 + j) * 3 + 1];
        xr[j][2] = xrow[(c0 + j) * 3 + 2];
      }
      #pragma unroll
      for (int r = 0; r < 16; r++) {
        const float* wp = W1_v + wu * 1024 + r * 64 + c0;  // uniform, k = wu
        #pragma unroll
        for (int j = 0; j < 16; j++) {
          float w = wp[j];
          acc[r][0] += w * xr[j][0];
          acc[r][1] += w * xr[j][1];
          acc[r][2] += w * xr[j][2];
        }
      }
    }
    __syncthreads();
    #pragma unroll
    for (int r = 0; r < 16; r++)
      #pragma unroll
      for (int i = 0; i < 3; i++)
        S[lane * 193 + wu * 48 + r * 3 + i] = acc[r][i];
    __syncthreads();
    for (int u = tid; u < nrem * 48; u += 256) {
      int n = u / 48, m4 = u - n * 48;
      const float* s = &S[n * 193 + m4 * 4];
      ((float4*)(P + (size_t)(n0 + n) * 816 + 48))[m4] = make_float4(s[0], s[1], s[2], s[3]);
    }
  }
  __syncthreads();

  // ============== Phase D1: xd(32, ij=0..4) -> Pd slots ij<5 (320) ==========
  for (int idx = tid; idx < nrem * 160; idx += 256) {
    int n = idx / 160, m = idx - n * 160, c = m / 5, ij = m - c * 5;
    S[n * 161 + m] = x_d[(size_t)(n0 + n) * 288 + c * 9 + ij];
  }
  __syncthreads();
  {
    float acc[16][5];
    #pragma unroll
    for (int r = 0; r < 16; r++)
      #pragma unroll
      for (int t = 0; t < 5; t++) acc[r][t] = 0.0f;
    const float* xrow = &S[lane * 161];
    for (int c0 = 0; c0 < 32; c0 += 8) {
      float xr[8][5];
      #pragma unroll
      for (int j = 0; j < 8; j++)
        #pragma unroll
        for (int t = 0; t < 5; t++) xr[j][t] = xrow[(c0 + j) * 5 + t];
      #pragma unroll
      for (int r = 0; r < 16; r++) {
        const float* wp = W1_d + wu * 512 + r * 32 + c0;   // uniform, k = wu
        #pragma unroll
        for (int j = 0; j < 8; j++) {
          float w = wp[j];
          #pragma unroll
          for (int t = 0; t < 5; t++) acc[r][t] += w * xr[j][t];
        }
      }
    }
    #pragma unroll
    for (int h = 0; h < 2; h++) {
      __syncthreads();
      if ((lane >> 5) == h) {
        int l5 = lane & 31;
        #pragma unroll
        for (int r = 0; r < 16; r++)
          #pragma unroll
          for (int t = 0; t < 5; t++)
            S[l5 * 321 + wu * 80 + r * 5 + t] = acc[r][t];
      }
      __syncthreads();
      int nbase = h * 32;
      int cnt = min(nrem - nbase, 32);
      for (int u = tid; u < cnt * 320; u += 256) {
        int n = u / 320, m = u - n * 320;
        int kk = m / 80, mm = m - kk * 80, rr = mm / 5, t = mm - rr * 5;
        P[(size_t)(n0 + nbase + n) * 816 + 240 + kk * 144 + 9 * rr + t] = S[n * 321 + m];
      }
    }
  }
  __syncthreads();

  // ============== Phase D2: xd(32, ij=5..8) -> Pd slots ij>=5 (256) =========
  for (int idx = tid; idx < nrem * 128; idx += 256) {
    int n = idx >> 7, m = idx & 127, c = m >> 2, t = m & 3;
    S[n * 129 + m] = x_d[(size_t)(n0 + n) * 288 + c * 9 + 5 + t];
  }
  __syncthreads();
  {
    float acc[16][4];
    #pragma unroll
    for (int r = 0; r < 16; r++)
      #pragma unroll
      for (int t = 0; t < 4; t++) acc[r][t] = 0.0f;
    const float* xrow = &S[lane * 129];
    for (int c0 = 0; c0 < 32; c0 += 8) {
      float xr[8][4];
      #pragma unroll
      for (int j = 0; j < 8; j++)
        #pragma unroll
        for (int t = 0; t < 4; t++) xr[j][t] = xrow[(c0 + j) * 4 + t];
      #pragma unroll
      for (int r = 0; r < 16; r++) {
        const float* wp = W1_d + wu * 512 + r * 32 + c0;   // uniform, k = wu
        #pragma unroll
        for (int j = 0; j < 8; j++) {
          float w = wp[j];
          #pragma unroll
          for (int t = 0; t < 4; t++) acc[r][t] += w * xr[j][t];
        }
      }
    }
    #pragma unroll
    for (int h = 0; h < 2; h++) {
      __syncthreads();
      if ((lane >> 5) == h) {
        int l5 = lane & 31;
        #pragma unroll
        for (int r = 0; r < 16; r++)
          #pragma unroll
          for (int t = 0; t < 4; t++)
            S[l5 * 257 + wu * 64 + r * 4 + t] = acc[r][t];
      }
      __syncthreads();
      int nbase = h * 32;
      int cnt = min(nrem - nbase, 32);
      for (int u = tid; u < cnt * 256; u += 256) {
        int n = u >> 8, m = u & 255;
        int kk = m >> 6, mm = m & 63, rr = mm >> 2, t = mm & 3;
        P[(size_t)(n0 + nbase + n) * 816 + 240 + kk * 144 + 9 * rr + 5 + t] = S[n * 257 + m];
      }
    }
  }
}

// ------------------- CSR build ---------------------------------------------
__global__ void hist_kernel(const int* __restrict__ src, int* __restrict__ counts, int E) {
  int e = blockIdx.x * 256 + threadIdx.x;
  if (e < E) atomicAdd(&counts[src[e]], 1);
}

__global__ __launch_bounds__(1024) void scan_kernel(
    const int* __restrict__ counts, int* __restrict__ offs, int* __restrict__ cursor,
    int N, int E)
{
  __shared__ int part[1024];
  int tid = threadIdx.x;
  int chunk = (N + 1023) / 1024;
  int lo = tid * chunk, hi = min(lo + chunk, N);
  int s = 0;
  for (int i = lo; i < hi; i++) s += counts[i];
  part[tid] = s;
  __syncthreads();
  for (int off = 1; off < 1024; off <<= 1) {
    int v = (tid >= off) ? part[tid - off] : 0;
    __syncthreads();
    part[tid] += v;
    __syncthreads();
  }
  int run = part[tid] - s;  // exclusive prefix of this thread's chunk
  for (int i = lo; i < hi; i++) { offs[i] = run; cursor[i] = run; run += counts[i]; }
  if (tid == 0) offs[N] = E;
}

__global__ void scatter_kernel(const int* __restrict__ src, int* __restrict__ cursor,
                               int* __restrict__ eidx, int E) {
  int e = blockIdx.x * 256 + threadIdx.x;
  if (e < E) { int p = atomicAdd(&cursor[src[e]], 1); eidx[p] = e; }
}

// ------------------- K2: 4 nodes per block (1 wave each), barrier-uniform ---
// Each 256-thread block = 4 waves, one node each, wave-private 1280-float LDS
// slice. Barriers are __syncthreads(); to keep trip counts uniform across the
// 4 waves, ALL waves loop to degmax = max(deg of the 4 nodes) and mask dead
// iterations with `live`.
// NOTE: no min-waves arg in __launch_bounds__. Capping VGPRs below ~100
// (rounds 2/3: caps 84/96) makes hipcc demote the per-lane arrays to scratch
// (VGPR_Count drops to 40-48, FETCH/WRITE explode). Uncapped regalloc lands
// at ~84-100 VGPR -> 5-6 waves/EU naturally.
__global__ __launch_bounds__(256) void node_gather_kernel(
    const float* __restrict__ r_ij, const int* __restrict__ dst,
    const int* __restrict__ offs, const int* __restrict__ eidx,
    const float* __restrict__ Pg, const float* __restrict__ W2,
    const float* __restrict__ Wo_a, const float* __restrict__ Wo_v, const float* __restrict__ Wo_d,
    float* __restrict__ out, int N)
{
  __shared__ __align__(16) float Sall[5120];    // 4 x 1280
  __shared__ int degs[4];
  const int wid = threadIdx.x >> 6;
  const int lane = threadIdx.x & 63;
  const int n = blockIdx.x * 4 + wid;
  const bool valid = (n < N);
  float* S = Sall + wid * 1280;
  float4* S4 = (float4*)S;
  const int off = valid ? offs[n] : 0;
  const int deg = valid ? (offs[n + 1] - off) : 0;
  if (lane == 0) degs[wid] = deg;

  // ---- per-lane slot constants (V slots p=0..2, D slots p=3..11) ----
  int aP[12], aQ[12], aF[12];
  unsigned typm = 0;  // bit p set => dot3-with-rv form
  #pragma unroll
  for (int p = 0; p < 3; p++) {
    int t = lane + 64 * p;                 // < 192 always
    int k = t / 48, m = t - 48 * k, jj = m >> 4, r = m & 15;
    int q_ = 816 + (3 + k) * 16 + r;       // q3..q6
    int P_, F_;
    if (k == 0)      { P_ = 16 + r;              F_ = 992 + jj; }
    else if (k == 1) { P_ = 48 + 3 * r + jj;     F_ = 995; }
    else if (k == 2) { P_ = 192 + 3 * r;         F_ = 992 + jj; typm |= 1u << p; }
    else             { P_ = 384 + 9 * r + 3 * jj; F_ = 995;     typm |= 1u << p; }
    aP[p] = P_; aQ[p] = q_; aF[p] = F_;
  }
  #pragma unroll
  for (int p = 0; p < 9; p++) {
    int u = lane + 64 * p;                 // < 576 always
    int s = u / 144, m = u - 144 * s, ij = m >> 4, r = m & 15;
    int i = ij / 3, jj = ij - 3 * i;
    int P_, F_, q_;
    if (s == 0)      { P_ = 32 + r;              q_ = 112 + r; F_ = 996 + ij; }
    else if (s == 1) { P_ = 144 + 3 * r + i;     q_ = 128 + r; F_ = 992 + jj; }
    else if (s == 2) { P_ = 240 + 9 * r + ij;    q_ = 144 + r; F_ = 995; }
    else             { P_ = 672 + 9 * r + 3 * i; q_ = 160 + r; F_ = 992 + jj; typm |= 1u << (3 + p); }
    aP[3 + p] = P_; aQ[3 + p] = 816 + q_; aF[3 + p] = F_;
  }
  const int ak = lane >> 4, ar = lane & 15;   // A slot (lane<48)

  // ---- hoist W2 rows for this lane's q slots ----
  float4 wqa[3], wqb[3];
  #pragma unroll
  for (int p = 0; p < 3; p++) {
    int tq = lane + 64 * p; if (tq > 175) tq = 175;
    const float4* w = (const float4*)(W2 + tq * 8);
    wqa[p] = w[0]; wqb[p] = w[1];
  }

  float accA = 0.0f, acc[12];
  #pragma unroll
  for (int p = 0; p < 12; p++) acc[p] = 0.0f;

  float4 pb0 = {}, pb1 = {}, pb2 = {}, pb3 = {};
  const int l3 = 192 + (lane < 12 ? lane : 0);

  __syncthreads();
  const int degmax = max(max(degs[0], degs[1]), max(degs[2], degs[3]));

  for (int base = 0; base < degmax; base += 64) {
    const int cnt = min(max(deg - base, 0), 64);      // this wave's live edges
    const int cntmax = min(degmax - base, 64);        // uniform trip count
    __syncthreads();
    if (lane < cnt) {
      int e = eidx[off + base + lane];
      float a = r_ij[3 * (size_t)e], b = r_ij[3 * (size_t)e + 1], c = r_ij[3 * (size_t)e + 2];
      S4[252 + lane] = make_float4(a, b, c, __int_as_float(dst[e]));
    }
    __syncthreads();
    // preload edge 0 of this chunk
    if (cnt > 0) {
      float4 me = S4[252];
      if (me.x * me.x + me.y * me.y + me.z * me.z < 5.0f) {
        const float4* Pp = (const float4*)(Pg + (size_t)__float_as_int(me.w) * 816);
        pb0 = Pp[lane]; pb1 = Pp[64 + lane]; pb2 = Pp[128 + lane]; pb3 = Pp[l3];
      }
    }
    for (int t = 0; t < cntmax; t++) {
      float4 me = S4[252 + t];
      float r0 = me.x, r1 = me.y, r2 = me.z;
      float rr = r0 * r0 + r1 * r1 + r2 * r2;
      bool live = (t < cnt) && (rr < 5.0f);
      float rv0 = 0, rv1 = 0, rv2 = 0;
      if (live) {
        float x_sq = rr * (1.0f / R0_F);
        float env = 1.0f - x_sq;
        // rv
        float v0 = r0 * (17.0f / R0_F), v1 = r1 * (17.0f / R0_F), v2 = r2 * (17.0f / R0_F);
        float nn = sqrtf(v0 * v0 + v1 * v1 + v2 * v2);
        float sig = 2.0f / (1.0f + __expf(-nn)) - 1.0f;
        float sc = sig / (nn + 1e-6f);
        rv0 = v0 * sc; rv1 = v1 * sc; rv2 = v2 * sc;
        // radial basis: cos(k*th)*env via Chebyshev
        float rad[8];
        {
          float c1 = __cosf(PI_F * sqrtf(x_sq));
          float two_c1 = 2.0f * c1, cm2 = 1.0f, cm1 = c1;
          rad[0] = env; rad[1] = c1 * env;
          #pragma unroll
          for (int k = 2; k < 8; k++) { float c = two_c1 * cm1 - cm2; rad[k] = c * env; cm2 = cm1; cm1 = c; }
        }
        float4 ra = make_float4(rad[0], rad[1], rad[2], rad[3]);
        float4 rb = make_float4(rad[4], rad[5], rad[6], rad[7]);
        // stage sP from prefetch regs
        S4[lane] = pb0; S4[64 + lane] = pb1; S4[128 + lane] = pb2;
        if (lane < 12) S4[192 + lane] = pb3;
        // q values
        S[816 + lane] = dot4(wqa[0], ra) + dot4(wqb[0], rb);
        S[880 + lane] = dot4(wqa[1], ra) + dot4(wqb[1], rb);
        if (lane < 48) S[944 + lane] = dot4(wqa[2], ra) + dot4(wqb[2], rb);
        // tables
        if (lane < 4) S[992 + lane] = (lane == 0) ? rv0 : (lane == 1) ? rv1 : (lane == 2) ? rv2 : 1.0f;
        if (lane >= 4 && lane < 13) {
          int ij = lane - 4, i = ij / 3, j = ij - 3 * i;
          float a = (i == 0) ? rv0 : (i == 1) ? rv1 : rv2;
          float b = (j == 0) ? rv0 : (j == 1) ? rv1 : rv2;
          S[992 + lane] = a * b;   // outer[ij] at 996+ij
        }
      }
      // prefetch next edge's P row (overlaps with accumulation)
      if (t + 1 < cnt) {
        float4 m2 = S4[252 + t + 1];
        if (m2.x * m2.x + m2.y * m2.y + m2.z * m2.z < 5.0f) {
          const float4* Pp = (const float4*)(Pg + (size_t)__float_as_int(m2.w) * 816);
          pb0 = Pp[lane]; pb1 = Pp[64 + lane]; pb2 = Pp[128 + lane]; pb3 = Pp[l3];
        }
      }
      __syncthreads();
      if (live) {
        // A slot
        if (lane < 48) {
          float v;
          if (ak == 0)      v = S[ar] * S[816 + ar];
          else if (ak == 1) v = (S[96 + 3 * ar] * rv0 + S[97 + 3 * ar] * rv1 + S[98 + 3 * ar] * rv2) * S[832 + ar];
          else {
            int b = 528 + 9 * ar;
            float o = (S[b] * rv0 + S[b + 3] * rv1 + S[b + 6] * rv2) * rv0
                    + (S[b + 1] * rv0 + S[b + 4] * rv1 + S[b + 7] * rv2) * rv1
                    + (S[b + 2] * rv0 + S[b + 5] * rv1 + S[b + 8] * rv2) * rv2;
            v = o * S[848 + ar];
          }
          accA += v;
        }
        // V + D slots, unified form
        #pragma unroll
        for (int p = 0; p < 12; p++) {
          float pv;
          if (typm & (1u << p)) pv = S[aP[p]] * rv0 + S[aP[p] + 1] * rv1 + S[aP[p] + 2] * rv2;
          else                  pv = S[aP[p]];
          acc[p] += pv * S[aQ[p]] * S[aF[p]];
        }
      }
      __syncthreads();
    }
  }

  // ---------------- epilogue: rank->channel, write out ----------------
  __syncthreads();
  if (lane < 48) S[lane] = accA;
  #pragma unroll
  for (int p = 0; p < 3; p++) S[48 + lane + 64 * p] = acc[p];
  #pragma unroll
  for (int p = 0; p < 9; p++) {
    int u = lane + 64 * p;
    int s = u / 144, m = u - 144 * s, ij = m >> 4, r = m & 15;
    S[240 + s * 180 + ij * 20 + r] = acc[3 + p];
  }
  __syncthreads();

  if (valid) {
    const size_t baseV = (size_t)N * 128;
    const size_t baseD = (size_t)N * 320;

    // B_a
    #pragma unroll
    for (int h = 0; h < 2; h++) {
      int c = lane + 64 * h;
      float a_ = 0.0f;
      #pragma unroll
      for (int k = 0; k < 3; k++) {
        const float4* w = (const float4*)(Wo_a + k * 2048 + c * 16);
        const float4* A4 = (const float4*)(&S[k * 16]);
        #pragma unroll
        for (int cc = 0; cc < 4; cc++) a_ += dot4(w[cc], A4[cc]);
      }
      out[(size_t)n * 128 + c] = a_;
    }
    // B_v (d = lane)
    {
      float o0 = 0, o1 = 0, o2 = 0;
      #pragma unroll
      for (int k = 0; k < 4; k++) {
        const float4* w = (const float4*)(Wo_v + k * 1024 + lane * 16);
        float4 w0 = w[0], w1 = w[1], w2 = w[2], w3 = w[3];
        #pragma unroll
        for (int j = 0; j < 3; j++) {
          const float4* A4 = (const float4*)(&S[48 + k * 48 + j * 16]);
          float v = dot4(w0, A4[0]) + dot4(w1, A4[1]) + dot4(w2, A4[2]) + dot4(w3, A4[3]);
          if (j == 0) o0 += v; else if (j == 1) o1 += v; else o2 += v;
        }
      }
      size_t ov = baseV + (size_t)n * 192 + lane * 3;
      out[ov] = o0; out[ov + 1] = o1; out[ov + 2] = o2;
    }
    // B_d
    #pragma unroll
    for (int p = 0; p < 5; p++) {
      int t = lane + 64 * p;
      if (t < 288) {
        int d = t / 9, ij = t - 9 * d;
        float a_ = 0.0f;
        #pragma unroll
        for (int s = 0; s < 4; s++) {
          const float4* w = (const float4*)(Wo_d + s * 512 + d * 16);
          const float4* A4 = (const float4*)(&S[240 + s * 180 + ij * 20]);
          a_ += dot4(w[0], A4[0]) + dot4(w[1], A4[1]) + dot4(w[2], A4[2]) + dot4(w[3], A4[3]);
        }
        out[baseD + (size_t)n * 288 + t] = a_;
      }
    }
  }
}

// ---------------------------------------------------------------------------
extern "C" void kernel_launch(void* const* d_in, const int* in_sizes, int n_in,
                              void* d_out, int out_size, void* d_ws, size_t ws_size,
                              hipStream_t stream) {
  const float* r_ij = (const float*)d_in[0];
  const float* x_a  = (const float*)d_in[1];
  const float* x_v  = (const float*)d_in[2];
  const float* x_d  = (const float*)d_in[3];
  const float* W1_a = (const float*)d_in[4];
  const float* W1_v = (const float*)d_in[5];
  const float* W1_d = (const float*)d_in[6];
  const float* W2   = (const float*)d_in[7];
  const float* Wo_a = (const float*)d_in[8];
  const float* Wo_v = (const float*)d_in[9];
  const float* Wo_d = (const float*)d_in[10];
  const int*  src   = (const int*)d_in[11];
  const int*  dst   = (const int*)d_in[12];

  const int E = in_sizes[0] / 3;
  const int N = in_sizes[1] / 128;

  float* P    = (float*)d_ws;
  int* counts = (int*)(P + (size_t)N * 816);
  int* offs   = counts + N;
  int* cursor = offs + N + 1;
  int* eidx   = cursor + N;

  hipMemsetAsync(counts, 0, sizeof(int) * (size_t)N, stream);

  hist_kernel<<<(E + 255) / 256, 256, 0, stream>>>(src, counts, E);
  scan_kernel<<<1, 1024, 0, stream>>>(counts, offs, cursor, N, E);
  scatter_kernel<<<(E + 255) / 256, 256, 0, stream>>>(src, cursor, eidx, E);
  node_proj_kernel<<<(N + 63) / 64, 256, 0, stream>>>(x_a, x_v, x_d, W1_a, W1_v, W1_d, P, N);
  node_gather_kernel<<<(N + 3) / 4, 256, 0, stream>>>(r_ij, dst, offs, eidx, P, W2,
                                                      Wo_a, Wo_v, Wo_d, (float*)d_out, N);
}

// Round 5
// 437.629 us; speedup vs baseline: 3.7459x; 1.1803x over previous
//
#include <hip/hip_runtime.h>
#include <hip/hip_bf16.h>
#include <math.h>

#define PI_F 3.14159265358979323846f
#define R0_F 5.0f

// ---------------------------------------------------------------------------
// ws layout:
//   P[n][816] float : per-node input projections
//     [0,48)    Pa[k*16+r]                 k=0:pa000,1:pa011,2:pa022
//     [48,240)  Pv[48+k*48+3r+i]           k=0:pv101,1:pv110,2:pv112,3:pv121
//     [240,816) Pd[240+k*144+9r+ij]        k=0:pd202,1:pd211,2:pd220,3:pd222
//   counts[N] | offs[N+1] | cursor[N] | eidx[E]   (ints, CSR by src)
// ---------------------------------------------------------------------------

static __device__ __forceinline__ float dot4(float4 a, float4 b) {
  return a.x * b.x + a.y * b.y + a.z * b.z + a.w * b.w;
}

// ------------------- K1: per-node input projections (v3: phase-split) -------
// blockIdx.y = phase (0:A, 1:V, 2:D1, 3:D2). Phases read disjoint x inputs
// and write disjoint P ranges -> independent blocks, 4x parallelism vs v2.
__global__ __launch_bounds__(256) void node_proj_kernel(
    const float* __restrict__ x_a, const float* __restrict__ x_v, const float* __restrict__ x_d,
    const float* __restrict__ W1_a, const float* __restrict__ W1_v, const float* __restrict__ W1_d,
    float* __restrict__ P, int N)
{
  __shared__ float S[12352];           // 48.25 KB
  const int tid = threadIdx.x;
  const int lane = tid & 63;
  const int wu = __builtin_amdgcn_readfirstlane(tid >> 6);  // uniform wave id 0..3
  const int n0 = blockIdx.x * 64;
  const int nrem = min(N - n0, 64);    // valid nodes in this block
  const int phase = blockIdx.y;

  if (phase == 0) {
    // ===================== Phase A: xa(128) -> Pa (48 slots) ================
    for (int idx4 = tid; idx4 < nrem * 32; idx4 += 256) {
      int n = idx4 >> 5, c4 = idx4 & 31;
      float4 v = ((const float4*)(x_a + (size_t)(n0 + n) * 128))[c4];
      float* d = &S[n * 129 + c4 * 4];
      d[0] = v.x; d[1] = v.y; d[2] = v.z; d[3] = v.w;
    }
    __syncthreads();
    float acc[12];
    #pragma unroll
    for (int q = 0; q < 12; q++) acc[q] = 0.0f;
    const float* xrow = &S[lane * 129];
    for (int c0 = 0; c0 < 128; c0 += 16) {
      float xr[16];
      #pragma unroll
      for (int j = 0; j < 16; j++) xr[j] = xrow[c0 + j];
      #pragma unroll
      for (int q = 0; q < 12; q++) {
        int o = wu * 12 + q;                       // uniform: slot = k*16+r = o
        const float* wp = W1_a + (o >> 4) * 2048 + (o & 15) * 128 + c0;
        float s = 0.0f;
        #pragma unroll
        for (int j = 0; j < 16; j++) s += wp[j] * xr[j];
        acc[q] += s;
      }
    }
    __syncthreads();
    #pragma unroll
    for (int q = 0; q < 12; q++) S[lane * 49 + wu * 12 + q] = acc[q];
    __syncthreads();
    for (int u = tid; u < nrem * 12; u += 256) {
      int n = u / 12, m4 = u - n * 12;
      const float* s = &S[n * 49 + m4 * 4];
      ((float4*)(P + (size_t)(n0 + n) * 816))[m4] = make_float4(s[0], s[1], s[2], s[3]);
    }
  } else if (phase == 1) {
    // ===================== Phase V: xv(64,3) -> Pv (192 slots) ==============
    for (int idx4 = tid; idx4 < nrem * 48; idx4 += 256) {
      int n = idx4 / 48, m4 = idx4 - n * 48;
      float4 v = ((const float4*)(x_v + (size_t)(n0 + n) * 192))[m4];
      float* d = &S[n * 193 + m4 * 4];
      d[0] = v.x; d[1] = v.y; d[2] = v.z; d[3] = v.w;
    }
    __syncthreads();
    float acc[16][3];
    #pragma unroll
    for (int r = 0; r < 16; r++)
      #pragma unroll
      for (int i = 0; i < 3; i++) acc[r][i] = 0.0f;
    const float* xrow = &S[lane * 193];
    for (int c0 = 0; c0 < 64; c0 += 16) {
      float xr[16][3];
      #pragma unroll
      for (int j = 0; j < 16; j++) {
        xr[j][0] = xrow[(c0 + j) * 3 + 0];
        xr[j][1] = xrow[(c0 + j) * 3 + 1];
        xr[j][2] = xrow[(c0 + j) * 3 + 2];
      }
      #pragma unroll
      for (int r = 0; r < 16; r++) {
        const float* wp = W1_v + wu * 1024 + r * 64 + c0;  // uniform, k = wu
        #pragma unroll
        for (int j = 0; j < 16; j++) {
          float w = wp[j];
          acc[r][0] += w * xr[j][0];
          acc[r][1] += w * xr[j][1];
          acc[r][2] += w * xr[j][2];
        }
      }
    }
    __syncthreads();
    #pragma unroll
    for (int r = 0; r < 16; r++)
      #pragma unroll
      for (int i = 0; i < 3; i++)
        S[lane * 193 + wu * 48 + r * 3 + i] = acc[r][i];
    __syncthreads();
    for (int u = tid; u < nrem * 48; u += 256) {
      int n = u / 48, m4 = u - n * 48;
      const float* s = &S[n * 193 + m4 * 4];
      ((float4*)(P + (size_t)(n0 + n) * 816 + 48))[m4] = make_float4(s[0], s[1], s[2], s[3]);
    }
  } else if (phase == 2) {
    // ============== Phase D1: xd(32, ij=0..4) -> Pd slots ij<5 (320) ========
    for (int idx = tid; idx < nrem * 160; idx += 256) {
      int n = idx / 160, m = idx - n * 160, c = m / 5, ij = m - c * 5;
      S[n * 161 + m] = x_d[(size_t)(n0 + n) * 288 + c * 9 + ij];
    }
    __syncthreads();
    float acc[16][5];
    #pragma unroll
    for (int r = 0; r < 16; r++)
      #pragma unroll
      for (int t = 0; t < 5; t++) acc[r][t] = 0.0f;
    const float* xrow = &S[lane * 161];
    for (int c0 = 0; c0 < 32; c0 += 8) {
      float xr[8][5];
      #pragma unroll
      for (int j = 0; j < 8; j++)
        #pragma unroll
        for (int t = 0; t < 5; t++) xr[j][t] = xrow[(c0 + j) * 5 + t];
      #pragma unroll
      for (int r = 0; r < 16; r++) {
        const float* wp = W1_d + wu * 512 + r * 32 + c0;   // uniform, k = wu
        #pragma unroll
        for (int j = 0; j < 8; j++) {
          float w = wp[j];
          #pragma unroll
          for (int t = 0; t < 5; t++) acc[r][t] += w * xr[j][t];
        }
      }
    }
    #pragma unroll
    for (int h = 0; h < 2; h++) {
      __syncthreads();
      if ((lane >> 5) == h) {
        int l5 = lane & 31;
        #pragma unroll
        for (int r = 0; r < 16; r++)
          #pragma unroll
          for (int t = 0; t < 5; t++)
            S[l5 * 321 + wu * 80 + r * 5 + t] = acc[r][t];
      }
      __syncthreads();
      int nbase = h * 32;
      int cnt = min(nrem - nbase, 32);
      for (int u = tid; u < cnt * 320; u += 256) {
        int n = u / 320, m = u - n * 320;
        int kk = m / 80, mm = m - kk * 80, rr = mm / 5, t = mm - rr * 5;
        P[(size_t)(n0 + nbase + n) * 816 + 240 + kk * 144 + 9 * rr + t] = S[n * 321 + m];
      }
    }
  } else {
    // ============== Phase D2: xd(32, ij=5..8) -> Pd slots ij>=5 (256) =======
    for (int idx = tid; idx < nrem * 128; idx += 256) {
      int n = idx >> 7, m = idx & 127, c = m >> 2, t = m & 3;
      S[n * 129 + m] = x_d[(size_t)(n0 + n) * 288 + c * 9 + 5 + t];
    }
    __syncthreads();
    float acc[16][4];
    #pragma unroll
    for (int r = 0; r < 16; r++)
      #pragma unroll
      for (int t = 0; t < 4; t++) acc[r][t] = 0.0f;
    const float* xrow = &S[lane * 129];
    for (int c0 = 0; c0 < 32; c0 += 8) {
      float xr[8][4];
      #pragma unroll
      for (int j = 0; j < 8; j++)
        #pragma unroll
        for (int t = 0; t < 4; t++) xr[j][t] = xrow[(c0 + j) * 4 + t];
      #pragma unroll
      for (int r = 0; r < 16; r++) {
        const float* wp = W1_d + wu * 512 + r * 32 + c0;   // uniform, k = wu
        #pragma unroll
        for (int j = 0; j < 8; j++) {
          float w = wp[j];
          #pragma unroll
          for (int t = 0; t < 4; t++) acc[r][t] += w * xr[j][t];
        }
      }
    }
    #pragma unroll
    for (int h = 0; h < 2; h++) {
      __syncthreads();
      if ((lane >> 5) == h) {
        int l5 = lane & 31;
        #pragma unroll
        for (int r = 0; r < 16; r++)
          #pragma unroll
          for (int t = 0; t < 4; t++)
            S[l5 * 257 + wu * 64 + r * 4 + t] = acc[r][t];
      }
      __syncthreads();
      int nbase = h * 32;
      int cnt = min(nrem - nbase, 32);
      for (int u = tid; u < cnt * 256; u += 256) {
        int n = u >> 8, m = u & 255;
        int kk = m >> 6, mm = m & 63, rr = mm >> 2, t = mm & 3;
        P[(size_t)(n0 + nbase + n) * 816 + 240 + kk * 144 + 9 * rr + 5 + t] = S[n * 257 + m];
      }
    }
  }
}

// ------------------- CSR build ---------------------------------------------
__global__ void hist_kernel(const int* __restrict__ src, int* __restrict__ counts, int E) {
  int e = blockIdx.x * 256 + threadIdx.x;
  if (e < E) atomicAdd(&counts[src[e]], 1);
}

__global__ __launch_bounds__(1024) void scan_kernel(
    const int* __restrict__ counts, int* __restrict__ offs, int* __restrict__ cursor,
    int N, int E)
{
  __shared__ int part[1024];
  int tid = threadIdx.x;
  int chunk = (N + 1023) / 1024;
  int lo = tid * chunk, hi = min(lo + chunk, N);
  int s = 0;
  for (int i = lo; i < hi; i++) s += counts[i];
  part[tid] = s;
  __syncthreads();
  for (int off = 1; off < 1024; off <<= 1) {
    int v = (tid >= off) ? part[tid - off] : 0;
    __syncthreads();
    part[tid] += v;
    __syncthreads();
  }
  int run = part[tid] - s;  // exclusive prefix of this thread's chunk
  for (int i = lo; i < hi; i++) { offs[i] = run; cursor[i] = run; run += counts[i]; }
  if (tid == 0) offs[N] = E;
}

__global__ void scatter_kernel(const int* __restrict__ src, int* __restrict__ cursor,
                               int* __restrict__ eidx, int E) {
  int e = blockIdx.x * 256 + threadIdx.x;
  if (e < E) { int p = atomicAdd(&cursor[src[e]], 1); eidx[p] = e; }
}

// ------------------- K2: 4 independent waves per block, barrier-free --------
// Each 256-thread block = 4 waves, one node each, wave-private 1280-float LDS
// slice. NO __syncthreads anywhere: all LDS producer/consumer pairs are
// within one wave (per-wave DS ops execute in order; the compiler inserts
// lgkmcnt waits for the register dependencies). This is exactly what
// round-1's 64-thread-block __syncthreads lowered to — but with 4x the
// workgroup density and no cross-wave padding (each wave loops its own deg).
// NOTE: no min-waves arg in __launch_bounds__, no inline asm — both caused
// the rounds-2/3 scratch cliff (VGPR cap < ~100 demotes the per-lane arrays
// to local memory; FETCH/WRITE explode).
// Per-wave LDS float map (1280):
//   [0,816)    sP  (gathered P[dst] for current edge)
//   [816,992)  sq  (q[i*16+r], 176)
//   [992,996)  rvtab: rv0,rv1,rv2,1.0
//   [996,1005) outer[ij] = rv_i*rv_j
//   [1008,1264) edge meta float4[64]: (r0,r1,r2, dst-as-float-bits)
// Epilogue reuses [0,960) as ACC.
__global__ __launch_bounds__(256) void node_gather_kernel(
    const float* __restrict__ r_ij, const int* __restrict__ dst,
    const int* __restrict__ offs, const int* __restrict__ eidx,
    const float* __restrict__ Pg, const float* __restrict__ W2,
    const float* __restrict__ Wo_a, const float* __restrict__ Wo_v, const float* __restrict__ Wo_d,
    float* __restrict__ out, int N)
{
  __shared__ __align__(16) float Sall[5120];    // 4 x 1280
  const int wid = threadIdx.x >> 6;
  const int lane = threadIdx.x & 63;
  const int n = blockIdx.x * 4 + wid;
  if (n >= N) return;
  float* S = Sall + wid * 1280;
  float4* S4 = (float4*)S;
  const int off = offs[n], deg = offs[n + 1] - off;

  // ---- per-lane slot constants (V slots p=0..2, D slots p=3..11) ----
  int aP[12], aQ[12], aF[12];
  unsigned typm = 0;  // bit p set => dot3-with-rv form
  #pragma unroll
  for (int p = 0; p < 3; p++) {
    int t = lane + 64 * p;                 // < 192 always
    int k = t / 48, m = t - 48 * k, jj = m >> 4, r = m & 15;
    int q_ = 816 + (3 + k) * 16 + r;       // q3..q6
    int P_, F_;
    if (k == 0)      { P_ = 16 + r;              F_ = 992 + jj; }
    else if (k == 1) { P_ = 48 + 3 * r + jj;     F_ = 995; }
    else if (k == 2) { P_ = 192 + 3 * r;         F_ = 992 + jj; typm |= 1u << p; }
    else             { P_ = 384 + 9 * r + 3 * jj; F_ = 995;     typm |= 1u << p; }
    aP[p] = P_; aQ[p] = q_; aF[p] = F_;
  }
  #pragma unroll
  for (int p = 0; p < 9; p++) {
    int u = lane + 64 * p;                 // < 576 always
    int s = u / 144, m = u - 144 * s, ij = m >> 4, r = m & 15;
    int i = ij / 3, jj = ij - 3 * i;
    int P_, F_, q_;
    if (s == 0)      { P_ = 32 + r;              q_ = 112 + r; F_ = 996 + ij; }
    else if (s == 1) { P_ = 144 + 3 * r + i;     q_ = 128 + r; F_ = 992 + jj; }
    else if (s == 2) { P_ = 240 + 9 * r + ij;    q_ = 144 + r; F_ = 995; }
    else             { P_ = 672 + 9 * r + 3 * i; q_ = 160 + r; F_ = 992 + jj; typm |= 1u << (3 + p); }
    aP[3 + p] = P_; aQ[3 + p] = 816 + q_; aF[3 + p] = F_;
  }
  const int ak = lane >> 4, ar = lane & 15;   // A slot (lane<48)

  // ---- hoist W2 rows for this lane's q slots ----
  float4 wqa[3], wqb[3];
  #pragma unroll
  for (int p = 0; p < 3; p++) {
    int tq = lane + 64 * p; if (tq > 175) tq = 175;
    const float4* w = (const float4*)(W2 + tq * 8);
    wqa[p] = w[0]; wqb[p] = w[1];
  }

  float accA = 0.0f, acc[12];
  #pragma unroll
  for (int p = 0; p < 12; p++) acc[p] = 0.0f;

  float4 pb0 = {}, pb1 = {}, pb2 = {}, pb3 = {};
  const int l3 = 192 + (lane < 12 ? lane : 0);

  for (int base = 0; base < deg; base += 64) {
    int cnt = min(deg - base, 64);
    if (lane < cnt) {
      int e = eidx[off + base + lane];
      float a = r_ij[3 * (size_t)e], b = r_ij[3 * (size_t)e + 1], c = r_ij[3 * (size_t)e + 2];
      S4[252 + lane] = make_float4(a, b, c, __int_as_float(dst[e]));
    }
    // preload edge 0 of this chunk
    {
      float4 me = S4[252];
      if (me.x * me.x + me.y * me.y + me.z * me.z < 5.0f) {
        const float4* Pp = (const float4*)(Pg + (size_t)__float_as_int(me.w) * 816);
        pb0 = Pp[lane]; pb1 = Pp[64 + lane]; pb2 = Pp[128 + lane]; pb3 = Pp[l3];
      }
    }
    for (int t = 0; t < cnt; t++) {
      float4 me = S4[252 + t];
      float r0 = me.x, r1 = me.y, r2 = me.z;
      float rr = r0 * r0 + r1 * r1 + r2 * r2;
      bool live = rr < 5.0f;
      float rv0 = 0, rv1 = 0, rv2 = 0;
      if (live) {
        float x_sq = rr * (1.0f / R0_F);
        float env = 1.0f - x_sq;
        // rv
        float v0 = r0 * (17.0f / R0_F), v1 = r1 * (17.0f / R0_F), v2 = r2 * (17.0f / R0_F);
        float nn = sqrtf(v0 * v0 + v1 * v1 + v2 * v2);
        float sig = 2.0f / (1.0f + __expf(-nn)) - 1.0f;
        float sc = sig / (nn + 1e-6f);
        rv0 = v0 * sc; rv1 = v1 * sc; rv2 = v2 * sc;
        // radial basis: cos(k*th)*env via Chebyshev
        float rad[8];
        {
          float c1 = __cosf(PI_F * sqrtf(x_sq));
          float two_c1 = 2.0f * c1, cm2 = 1.0f, cm1 = c1;
          rad[0] = env; rad[1] = c1 * env;
          #pragma unroll
          for (int k = 2; k < 8; k++) { float c = two_c1 * cm1 - cm2; rad[k] = c * env; cm2 = cm1; cm1 = c; }
        }
        float4 ra = make_float4(rad[0], rad[1], rad[2], rad[3]);
        float4 rb = make_float4(rad[4], rad[5], rad[6], rad[7]);
        // stage sP from prefetch regs
        S4[lane] = pb0; S4[64 + lane] = pb1; S4[128 + lane] = pb2;
        if (lane < 12) S4[192 + lane] = pb3;
        // q values
        S[816 + lane] = dot4(wqa[0], ra) + dot4(wqb[0], rb);
        S[880 + lane] = dot4(wqa[1], ra) + dot4(wqb[1], rb);
        if (lane < 48) S[944 + lane] = dot4(wqa[2], ra) + dot4(wqb[2], rb);
        // tables
        if (lane < 4) S[992 + lane] = (lane == 0) ? rv0 : (lane == 1) ? rv1 : (lane == 2) ? rv2 : 1.0f;
        if (lane >= 4 && lane < 13) {
          int ij = lane - 4, i = ij / 3, j = ij - 3 * i;
          float a = (i == 0) ? rv0 : (i == 1) ? rv1 : rv2;
          float b = (j == 0) ? rv0 : (j == 1) ? rv1 : rv2;
          S[992 + lane] = a * b;   // outer[ij] at 996+ij
        }
      }
      // prefetch next edge's P row (overlaps with accumulation)
      if (t + 1 < cnt) {
        float4 m2 = S4[252 + t + 1];
        if (m2.x * m2.x + m2.y * m2.y + m2.z * m2.z < 5.0f) {
          const float4* Pp = (const float4*)(Pg + (size_t)__float_as_int(m2.w) * 816);
          pb0 = Pp[lane]; pb1 = Pp[64 + lane]; pb2 = Pp[128 + lane]; pb3 = Pp[l3];
        }
      }
      if (live) {
        // A slot
        if (lane < 48) {
          float v;
          if (ak == 0)      v = S[ar] * S[816 + ar];
          else if (ak == 1) v = (S[96 + 3 * ar] * rv0 + S[97 + 3 * ar] * rv1 + S[98 + 3 * ar] * rv2) * S[832 + ar];
          else {
            int b = 528 + 9 * ar;
            float o = (S[b] * rv0 + S[b + 3] * rv1 + S[b + 6] * rv2) * rv0
                    + (S[b + 1] * rv0 + S[b + 4] * rv1 + S[b + 7] * rv2) * rv1
                    + (S[b + 2] * rv0 + S[b + 5] * rv1 + S[b + 8] * rv2) * rv2;
            v = o * S[848 + ar];
          }
          accA += v;
        }
        // V + D slots, unified form
        #pragma unroll
        for (int p = 0; p < 12; p++) {
          float pv;
          if (typm & (1u << p)) pv = S[aP[p]] * rv0 + S[aP[p] + 1] * rv1 + S[aP[p] + 2] * rv2;
          else                  pv = S[aP[p]];
          acc[p] += pv * S[aQ[p]] * S[aF[p]];
        }
      }
    }
  }

  // ---------------- epilogue: rank->channel, write out ----------------
  if (lane < 48) S[lane] = accA;
  #pragma unroll
  for (int p = 0; p < 3; p++) S[48 + lane + 64 * p] = acc[p];
  #pragma unroll
  for (int p = 0; p < 9; p++) {
    int u = lane + 64 * p;
    int s = u / 144, m = u - 144 * s, ij = m >> 4, r = m & 15;
    S[240 + s * 180 + ij * 20 + r] = acc[3 + p];
  }

  const size_t baseV = (size_t)N * 128;
  const size_t baseD = (size_t)N * 320;

  // B_a
  #pragma unroll
  for (int h = 0; h < 2; h++) {
    int c = lane + 64 * h;
    float a_ = 0.0f;
    #pragma unroll
    for (int k = 0; k < 3; k++) {
      const float4* w = (const float4*)(Wo_a + k * 2048 + c * 16);
      const float4* A4 = (const float4*)(&S[k * 16]);
      #pragma unroll
      for (int cc = 0; cc < 4; cc++) a_ += dot4(w[cc], A4[cc]);
    }
    out[(size_t)n * 128 + c] = a_;
  }
  // B_v (d = lane)
  {
    float o0 = 0, o1 = 0, o2 = 0;
    #pragma unroll
    for (int k = 0; k < 4; k++) {
      const float4* w = (const float4*)(Wo_v + k * 1024 + lane * 16);
      float4 w0 = w[0], w1 = w[1], w2 = w[2], w3 = w[3];
      #pragma unroll
      for (int j = 0; j < 3; j++) {
        const float4* A4 = (const float4*)(&S[48 + k * 48 + j * 16]);
        float v = dot4(w0, A4[0]) + dot4(w1, A4[1]) + dot4(w2, A4[2]) + dot4(w3, A4[3]);
        if (j == 0) o0 += v; else if (j == 1) o1 += v; else o2 += v;
      }
    }
    size_t ov = baseV + (size_t)n * 192 + lane * 3;
    out[ov] = o0; out[ov + 1] = o1; out[ov + 2] = o2;
  }
  // B_d
  #pragma unroll
  for (int p = 0; p < 5; p++) {
    int t = lane + 64 * p;
    if (t < 288) {
      int d = t / 9, ij = t - 9 * d;
      float a_ = 0.0f;
      #pragma unroll
      for (int s = 0; s < 4; s++) {
        const float4* w = (const float4*)(Wo_d + s * 512 + d * 16);
        const float4* A4 = (const float4*)(&S[240 + s * 180 + ij * 20]);
        a_ += dot4(w[0], A4[0]) + dot4(w[1], A4[1]) + dot4(w[2], A4[2]) + dot4(w[3], A4[3]);
      }
      out[baseD + (size_t)n * 288 + t] = a_;
    }
  }
}

// ---------------------------------------------------------------------------
extern "C" void kernel_launch(void* const* d_in, const int* in_sizes, int n_in,
                              void* d_out, int out_size, void* d_ws, size_t ws_size,
                              hipStream_t stream) {
  const float* r_ij = (const float*)d_in[0];
  const float* x_a  = (const float*)d_in[1];
  const float* x_v  = (const float*)d_in[2];
  const float* x_d  = (const float*)d_in[3];
  const float* W1_a = (const float*)d_in[4];
  const float* W1_v = (const float*)d_in[5];
  const float* W1_d = (const float*)d_in[6];
  const float* W2   = (const float*)d_in[7];
  const float* Wo_a = (const float*)d_in[8];
  const float* Wo_v = (const float*)d_in[9];
  const float* Wo_d = (const float*)d_in[10];
  const int*  src   = (const int*)d_in[11];
  const int*  dst   = (const int*)d_in[12];

  const int E = in_sizes[0] / 3;
  const int N = in_sizes[1] / 128;

  float* P    = (float*)d_ws;
  int* counts = (int*)(P + (size_t)N * 816);
  int* offs   = counts + N;
  int* cursor = offs + N + 1;
  int* eidx   = cursor + N;

  hipMemsetAsync(counts, 0, sizeof(int) * (size_t)N, stream);

  hist_kernel<<<(E + 255) / 256, 256, 0, stream>>>(src, counts, E);
  scan_kernel<<<1, 1024, 0, stream>>>(counts, offs, cursor, N, E);
  scatter_kernel<<<(E + 255) / 256, 256, 0, stream>>>(src, cursor, eidx, E);
  dim3 g1((N + 63) / 64, 4);
  node_proj_kernel<<<g1, 256, 0, stream>>>(x_a, x_v, x_d, W1_a, W1_v, W1_d, P, N);
  node_gather_kernel<<<(N + 3) / 4, 256, 0, stream>>>(r_ij, dst, offs, eidx, P, W2,
                                                      Wo_a, Wo_v, Wo_d, (float*)d_out, N);
}